// Round 2
// baseline (3485.303 us; speedup 1.0000x reference)
//
#include <hip/hip_runtime.h>
#include <hip/hip_bf16.h>

#define D_MODEL 512
#define HEADS   8
#define DK      64
#define D_FF    1024
#define SEQ     2048
#define BATCH   4
#define NTOK    (BATCH*SEQ)          // 8192 rows
#define NELEM   (NTOK*D_MODEL)       // 4,194,304

__device__ __forceinline__ float bflo(unsigned u){ return __uint_as_float(u << 16); }
__device__ __forceinline__ float bfhi(unsigned u){ return __uint_as_float(u & 0xffff0000u); }

__device__ __forceinline__ float ldf(const void* p, size_t i, int f32) {
    return f32 ? ((const float*)p)[i] : __bfloat162float(((const __hip_bfloat16*)p)[i]);
}

// ---------------- dtype detector ----------------
// If inputs are fp32 interpreted as bf16, the low 16 bits of ~1/256 words form
// bf16 NaN/Inf (exp bits all 1). True bf16 N(0,1) data has none. flags[0]=1 -> fp32.
__global__ void detect_k(const unsigned* __restrict__ w, int* __restrict__ flags) {
    __shared__ int found;
    if (threadIdx.x == 0) found = 0;
    __syncthreads();
    int hit = 0;
    for (int i = threadIdx.x; i < 65536; i += 256) {
        unsigned lo = w[i] & 0xFFFFu;
        if ((lo & 0x7F80u) == 0x7F80u) hit = 1;
    }
    if (hit) atomicOr(&found, 1);
    __syncthreads();
    if (threadIdx.x == 0) { flags[0] = found ? 1 : 0; flags[1] = 1; }
}

// ---------------- casts ----------------
__global__ void cast_in_k(const void* __restrict__ in, const int* __restrict__ flagp,
                          float* __restrict__ out, int n) {
    int f32 = *flagp;
    int i = blockIdx.x * blockDim.x + threadIdx.x;
    if (i < n) out[i] = ldf(in, i, f32);
}

__global__ void cast_out_k(const float* __restrict__ in, const int* __restrict__ flagp,
                           void* __restrict__ out, int n) {
    int f32 = *flagp;
    int i = blockIdx.x * blockDim.x + threadIdx.x;
    if (i < n) {
        if (f32) ((float*)out)[i] = in[i];
        else     ((__hip_bfloat16*)out)[i] = __float2bfloat16(in[i]);
    }
}

// ---------------- layernorm: one wave per row (512 cols, 8/lane) ----------------
__global__ __launch_bounds__(256)
void layernorm_k(const float* __restrict__ x, const void* __restrict__ g,
                 const void* __restrict__ b, const int* __restrict__ flagp,
                 float* __restrict__ y) {
    int f32  = *flagp;
    int row  = blockIdx.x * 4 + (threadIdx.x >> 6);
    int lane = threadIdx.x & 63;
    const float* xr = x + (size_t)row * D_MODEL;
    float v[8];
    float s = 0.f;
    #pragma unroll
    for (int i = 0; i < 8; i++) { v[i] = xr[lane + i*64]; s += v[i]; }
    #pragma unroll
    for (int off = 32; off; off >>= 1) s += __shfl_xor(s, off);
    float mu = s * (1.f / D_MODEL);
    float ss = 0.f;
    #pragma unroll
    for (int i = 0; i < 8; i++) { float d = v[i] - mu; ss += d * d; }
    #pragma unroll
    for (int off = 32; off; off >>= 1) ss += __shfl_xor(ss, off);
    float rstd = rsqrtf(ss * (1.f / D_MODEL) + 1e-5f);
    float* yr = y + (size_t)row * D_MODEL;
    #pragma unroll
    for (int i = 0; i < 8; i++) {
        int c = lane + i*64;
        yr[c] = (v[i] - mu) * rstd * ldf(g, c, f32) + ldf(b, c, f32);
    }
}

// ---------------- flash-style attention ----------------
// One block = 8 query rows of one (b,h). 256 threads, K-chunks of 256.
// Q fp32 (LN output). K/V dtype selected by *kvf32p (1=fp32, 0=bf16).
// Xout[(b,s),D] += softmax(QK^T/8 [masked]) @ V   (residual fused)
template<bool HAS_MASK>
__global__ __launch_bounds__(256)
void attn_k(const float* __restrict__ Q, const void* __restrict__ Kp, const void* __restrict__ Vp,
            const int* __restrict__ kvf32p, const int* __restrict__ mask, float* __restrict__ Xout) {
    const int QROWS = 8, CH = 256;
    int kvf32 = *kvf32p;
    int bid = blockIdx.x;
    int qb = bid & 255;          // 2048/8 = 256 q-blocks
    int h  = (bid >> 8) & 7;
    int b  = bid >> 11;
    int q0 = qb * QROWS;
    int tid = threadIdx.x;

    __shared__ float qs[QROWS][DK];
    __shared__ float sc[QROWS][CH];
    __shared__ float mrow[QROWS], lrow[QROWS], arow[QROWS], tmp8[QROWS];

    for (int i = tid; i < QROWS * DK; i += 256) {
        int r = i >> 6, d = i & 63;
        qs[r][d] = Q[((size_t)(b*SEQ + q0 + r))*D_MODEL + h*DK + d] * 0.125f; // 1/sqrt(64)
    }
    if (tid < QROWS) { mrow[tid] = -INFINITY; lrow[tid] = 0.f; }
    __syncthreads();

    const size_t kbase = (size_t)b * SEQ * D_MODEL + (size_t)h * DK;
    float o[QROWS];
    #pragma unroll
    for (int r = 0; r < QROWS; r++) o[r] = 0.f;
    int d_own = tid & 63;
    int seg   = tid >> 6;

    for (int k0 = 0; k0 < SEQ; k0 += CH) {
        int j = k0 + tid;
        float s[QROWS];
        #pragma unroll
        for (int r = 0; r < QROWS; r++) s[r] = 0.f;

        if (kvf32) {
            const float4* K4 = reinterpret_cast<const float4*>(
                (const float*)Kp + kbase + (size_t)j * D_MODEL);
            #pragma unroll
            for (int dq = 0; dq < 16; dq++) {
                float4 kv = K4[dq];
                #pragma unroll
                for (int r = 0; r < QROWS; r++) {
                    s[r] += qs[r][dq*4+0]*kv.x + qs[r][dq*4+1]*kv.y
                          + qs[r][dq*4+2]*kv.z + qs[r][dq*4+3]*kv.w;
                }
            }
        } else {
            const uint4* K4 = reinterpret_cast<const uint4*>(
                (const __hip_bfloat16*)Kp + kbase + (size_t)j * D_MODEL);
            #pragma unroll
            for (int dq = 0; dq < 8; dq++) {
                uint4 u = K4[dq];
                float f0 = bflo(u.x), f1 = bfhi(u.x), f2 = bflo(u.y), f3 = bfhi(u.y);
                float f4 = bflo(u.z), f5 = bfhi(u.z), f6 = bflo(u.w), f7 = bfhi(u.w);
                #pragma unroll
                for (int r = 0; r < QROWS; r++) {
                    s[r] += qs[r][dq*8+0]*f0 + qs[r][dq*8+1]*f1 + qs[r][dq*8+2]*f2 + qs[r][dq*8+3]*f3
                          + qs[r][dq*8+4]*f4 + qs[r][dq*8+5]*f5 + qs[r][dq*8+6]*f6 + qs[r][dq*8+7]*f7;
                }
            }
        }

        if (HAS_MASK) {
            const int* mp = mask + ((size_t)(b*SEQ + q0)) * SEQ + j;
            #pragma unroll
            for (int r = 0; r < QROWS; r++)
                if (mp[(size_t)r * SEQ] == 0) s[r] = -1e9f;
        }

        #pragma unroll
        for (int r = 0; r < QROWS; r++) sc[r][tid] = s[r];
        __syncthreads();

        { // per-row max: 32 threads per row (shfl stays inside 32-lane half-wave)
            int r = tid >> 5, i = tid & 31;
            float v = sc[r][i];
            #pragma unroll
            for (int k = 1; k < 8; k++) v = fmaxf(v, sc[r][i + k*32]);
            #pragma unroll
            for (int off = 16; off; off >>= 1) v = fmaxf(v, __shfl_xor(v, off));
            if (i == 0) {
                float mold = mrow[r];
                float mnew = fmaxf(mold, v);
                mrow[r] = mnew;
                arow[r] = __expf(mold - mnew);   // exp(-inf)=0 first chunk
            }
        }
        __syncthreads();

        #pragma unroll
        for (int r = 0; r < QROWS; r++) {
            float p = __expf(s[r] - mrow[r]);
            sc[r][tid] = p;                      // overwrite scores with p
        }
        __syncthreads();

        { // per-row sum of p
            int r = tid >> 5, i = tid & 31;
            float v = sc[r][i];
            #pragma unroll
            for (int k = 1; k < 8; k++) v += sc[r][i + k*32];
            #pragma unroll
            for (int off = 16; off; off >>= 1) v += __shfl_xor(v, off);
            if (i == 0) tmp8[r] = v;
        }
        __syncthreads();

        if (tid < QROWS) lrow[tid] = lrow[tid] * arow[tid] + tmp8[tid];

        #pragma unroll
        for (int r = 0; r < QROWS; r++) o[r] *= arow[r];

        // PV: thread owns (d_own, seg); wave-uniform seg -> coalesced V reads
        for (int jj = 0; jj < 64; jj++) {
            int j2 = k0 + seg*64 + jj;
            size_t vidx = kbase + (size_t)j2 * D_MODEL + d_own;
            float vv = kvf32 ? ((const float*)Vp)[vidx]
                             : __bfloat162float(((const __hip_bfloat16*)Vp)[vidx]);
            #pragma unroll
            for (int r = 0; r < QROWS; r++) o[r] += sc[r][seg*64 + jj] * vv;
        }
        __syncthreads();   // protect sc/arow before next chunk
    }

    // combine 4 segment partials per row, divide by l, residual-add
    float* scratch = &sc[0][0];
    for (int r = 0; r < QROWS; r++) {
        scratch[tid] = o[r];
        __syncthreads();
        if (tid < 64) {
            float ot = scratch[tid] + scratch[tid+64] + scratch[tid+128] + scratch[tid+192];
            size_t idx = ((size_t)(b*SEQ + q0 + r)) * D_MODEL + (size_t)h * DK + tid;
            Xout[idx] += ot / lrow[r];
        }
        __syncthreads();
    }
}

// ---------------- tiled GEMM (vector fp32), 64x64 tile, 4x4 per thread ----------------
// C[M,N] = A[M,KTOT] @ B[KTOT,N] + bias. A fp32; B/bias dtype by flag.
// RELU_STORE: C = relu(v); else C += v.
template<int KTOT, bool RELU_STORE>
__global__ __launch_bounds__(256)
void gemm_k(const float* __restrict__ Ap, const void* __restrict__ Bp,
            const void* __restrict__ bias, const int* __restrict__ flagp,
            float* __restrict__ Cp, int N) {
    int f32 = *flagp;
    __shared__ float As[16][65];
    __shared__ float Bs[16][65];
    int tid = threadIdx.x;
    int tx = tid & 15, ty = tid >> 4;
    int r0 = blockIdx.y * 64;
    int c0 = blockIdx.x * 64;
    float acc[4][4] = {};

    for (int k0 = 0; k0 < KTOT; k0 += 16) {
        for (int idx = tid; idx < 1024; idx += 256) {
            int m = idx >> 4, k = idx & 15;
            As[k][m] = Ap[(size_t)(r0+m)*KTOT + k0 + k];
        }
        for (int idx = tid; idx < 1024; idx += 256) {
            int k = idx >> 6, c = idx & 63;
            Bs[k][c] = ldf(Bp, (size_t)(k0+k)*N + c0 + c, f32);
        }
        __syncthreads();
        #pragma unroll
        for (int kk = 0; kk < 16; kk++) {
            float a[4], bb[4];
            #pragma unroll
            for (int i = 0; i < 4; i++) a[i] = As[kk][ty*4 + i];
            #pragma unroll
            for (int jv = 0; jv < 4; jv++) bb[jv] = Bs[kk][tx*4 + jv];
            #pragma unroll
            for (int i = 0; i < 4; i++)
                #pragma unroll
                for (int jv = 0; jv < 4; jv++)
                    acc[i][jv] += a[i] * bb[jv];
        }
        __syncthreads();
    }

    #pragma unroll
    for (int i = 0; i < 4; i++) {
        int m = r0 + ty*4 + i;
        #pragma unroll
        for (int jv = 0; jv < 4; jv++) {
            int c = c0 + tx*4 + jv;
            float v = acc[i][jv] + ldf(bias, c, f32);
            if (RELU_STORE) Cp[(size_t)m * N + c] = fmaxf(v, 0.f);
            else            Cp[(size_t)m * N + c] += v;
        }
    }
}

// ---------------- launch ----------------
extern "C" void kernel_launch(void* const* d_in, const int* in_sizes, int n_in,
                              void* d_out, int out_size, void* d_ws, size_t ws_size,
                              hipStream_t stream) {
    const void* x    = d_in[0];
    const void* enc  = d_in[1];
    const int*  mask = (const int*)d_in[2];
    const void* ln1g = d_in[3];
    const void* ln1b = d_in[4];
    const void* ln2g = d_in[5];
    const void* ln2b = d_in[6];
    const void* ln3g = d_in[7];
    const void* ln3b = d_in[8];
    const void* W1   = d_in[9];
    const void* b1   = d_in[10];
    const void* W2   = d_in[11];
    const void* b2   = d_in[12];

    float* bufX = (float*)d_ws;                   // running residual fp32 [8192,512]  16MB
    float* bufN = bufX + NELEM;                   // LN output fp32                    16MB
    float* bufH = bufN + NELEM;                   // FFN hidden fp32 [8192,1024]       32MB
    int*   flags = (int*)(bufH + (size_t)NTOK * D_FF); // flags[0]=f32-inputs, flags[1]=1

    dim3 blk(256);
    detect_k<<<1, blk, 0, stream>>>((const unsigned*)x, flags);
    // x -> fp32 running buffer
    cast_in_k<<<NELEM/256, blk, 0, stream>>>(x, flags, bufX, NELEM);
    // LN1 + masked self-attention + residual (K/V fp32 -> flags+1)
    layernorm_k<<<NTOK/4, blk, 0, stream>>>(bufX, ln1g, ln1b, flags, bufN);
    attn_k<true><<<BATCH*HEADS*(SEQ/8), blk, 0, stream>>>(bufN, bufN, bufN, flags+1, mask, bufX);
    // LN2 + cross-attention (K,V = encoder, dtype by flag) + residual
    layernorm_k<<<NTOK/4, blk, 0, stream>>>(bufX, ln2g, ln2b, flags, bufN);
    attn_k<false><<<BATCH*HEADS*(SEQ/8), blk, 0, stream>>>(bufN, enc, enc, flags, nullptr, bufX);
    // LN3 + FFN + residual
    layernorm_k<<<NTOK/4, blk, 0, stream>>>(bufX, ln3g, ln3b, flags, bufN);
    gemm_k<D_MODEL, true ><<<dim3(D_FF/64,    NTOK/64), blk, 0, stream>>>(bufN, W1, b1, flags, bufH, D_FF);
    gemm_k<D_FF,    false><<<dim3(D_MODEL/64, NTOK/64), blk, 0, stream>>>(bufH, W2, b2, flags, bufX, D_MODEL);
    // final cast (dtype by flag)
    cast_out_k<<<NELEM/256, blk, 0, stream>>>(bufX, flags, d_out, NELEM);
}

// Round 3
// 584.561 us; speedup vs baseline: 5.9623x; 5.9623x over previous
//
#include <hip/hip_runtime.h>
#include <hip/hip_bf16.h>

#define D_MODEL 512
#define HEADS   8
#define DK      64
#define D_FF    1024
#define SEQ     2048
#define BATCH   4
#define NTOK    (BATCH*SEQ)          // 8192 rows
#define NELEM   (NTOK*D_MODEL)       // 4,194,304

typedef __attribute__((ext_vector_type(8))) short bf8_t;   // 8 bf16 (4 VGPRs)
typedef __attribute__((ext_vector_type(4))) float f4_t;    // 4 fp32

#define GLD16(gp, lp) __builtin_amdgcn_global_load_lds( \
    (const __attribute__((address_space(1))) void*)(gp), \
    (__attribute__((address_space(3))) void*)(lp), 16, 0, 0)

__device__ __forceinline__ float ldf(const void* p, size_t i, int f32) {
    return f32 ? ((const float*)p)[i] : __bfloat162float(((const __hip_bfloat16*)p)[i]);
}
__device__ __forceinline__ short f2bf(float f) {
    union { __hip_bfloat16 h; short s; } u; u.h = __float2bfloat16(f); return u.s;
}

// ---------------- dtype detector (bf16 vs fp32 inputs) ----------------
__global__ void detect_k(const unsigned* __restrict__ w, int* __restrict__ flags) {
    __shared__ int found;
    if (threadIdx.x == 0) found = 0;
    __syncthreads();
    int hit = 0;
    for (int i = threadIdx.x; i < 65536; i += 256) {
        unsigned lo = w[i] & 0xFFFFu;
        if ((lo & 0x7F80u) == 0x7F80u) hit = 1;
    }
    if (hit) atomicOr(&found, 1);
    __syncthreads();
    if (threadIdx.x == 0) flags[0] = found ? 1 : 0;
}

// ---------------- casts ----------------
__global__ void cast_in_k(const void* __restrict__ in, const int* __restrict__ flagp,
                          float* __restrict__ out, int n) {
    int f32 = *flagp;
    int i = blockIdx.x * blockDim.x + threadIdx.x;
    if (i < n) out[i] = ldf(in, i, f32);
}
__global__ void cast_bf16_k(const void* __restrict__ in, const int* __restrict__ flagp,
                            __hip_bfloat16* __restrict__ out, int n) {
    int f32 = *flagp;
    int i = blockIdx.x * blockDim.x + threadIdx.x;
    if (i < n) out[i] = __float2bfloat16(ldf(in, i, f32));
}
__global__ void cast_out_k(const float* __restrict__ in, const int* __restrict__ flagp,
                           void* __restrict__ out, int n) {
    int f32 = *flagp;
    int i = blockIdx.x * blockDim.x + threadIdx.x;
    if (i < n) {
        if (f32) ((float*)out)[i] = in[i];
        else     ((__hip_bfloat16*)out)[i] = __float2bfloat16(in[i]);
    }
}

// ---------------- mask -> bitmask (64MB int32 -> 2MB bits, L2-resident) ----------------
__global__ __launch_bounds__(256)
void maskbits_k(const int* __restrict__ mask, unsigned* __restrict__ mb) {
    int row  = blockIdx.x * 4 + (threadIdx.x >> 6);
    int lane = threadIdx.x & 63;
    const int* mr = mask + (size_t)row * SEQ;
    for (int it = 0; it < SEQ/64; it++) {
        unsigned long long bal = __ballot(mr[it*64 + lane] != 0);
        if (lane == 0)  mb[(size_t)row*(SEQ/32) + it*2]     = (unsigned)bal;
        if (lane == 32) mb[(size_t)row*(SEQ/32) + it*2 + 1] = (unsigned)(bal >> 32);
    }
}

// ---------------- layernorm (fp32 in, bf16 out): one wave per row ----------------
__global__ __launch_bounds__(256)
void layernorm_k(const float* __restrict__ x, const void* __restrict__ g,
                 const void* __restrict__ b, const int* __restrict__ flagp,
                 __hip_bfloat16* __restrict__ y) {
    int f32  = *flagp;
    int row  = blockIdx.x * 4 + (threadIdx.x >> 6);
    int lane = threadIdx.x & 63;
    const float* xr = x + (size_t)row * D_MODEL;
    float v[8];
    float s = 0.f;
    #pragma unroll
    for (int i = 0; i < 8; i++) { v[i] = xr[lane + i*64]; s += v[i]; }
    #pragma unroll
    for (int off = 32; off; off >>= 1) s += __shfl_xor(s, off);
    float mu = s * (1.f / D_MODEL);
    float ss = 0.f;
    #pragma unroll
    for (int i = 0; i < 8; i++) { float d = v[i] - mu; ss += d * d; }
    #pragma unroll
    for (int off = 32; off; off >>= 1) ss += __shfl_xor(ss, off);
    float rstd = rsqrtf(ss * (1.f / D_MODEL) + 1e-5f);
    __hip_bfloat16* yr = y + (size_t)row * D_MODEL;
    #pragma unroll
    for (int i = 0; i < 8; i++) {
        int c = lane + i*64;
        yr[c] = __float2bfloat16((v[i] - mu) * rstd * ldf(g, c, f32) + ldf(b, c, f32));
    }
}

// ---------------- transpose (+cast) weights: dst[N][K] = src[K][N] ----------------
__global__ __launch_bounds__(256)
void transpose_k(const void* __restrict__ src, const int* __restrict__ flagp,
                 __hip_bfloat16* __restrict__ dst, int K, int N) {
    int f32 = *flagp;
    __shared__ __hip_bfloat16 t[32][33];
    int bx = blockIdx.x * 32, by = blockIdx.y * 32;   // bx: n-base, by: k-base
    int tx = threadIdx.x & 31, ty = threadIdx.x >> 5; // ty 0..7
    #pragma unroll
    for (int j = 0; j < 32; j += 8) {
        int k = by + ty + j, n = bx + tx;
        t[ty + j][tx] = __float2bfloat16(ldf(src, (size_t)k * N + n, f32));
    }
    __syncthreads();
    #pragma unroll
    for (int j = 0; j < 32; j += 8) {
        int n = bx + ty + j, k = by + tx;
        dst[(size_t)n * K + k] = t[tx][ty + j];
    }
}

// ---------------- MFMA flash attention ----------------
// Block: 64 q-rows of one (b,h); 4 waves x 16 rows. K-tiles of 64 keys.
// Q/K/V bf16 [NTOK, D_MODEL] head-sliced. Xout fp32 += softmax(QK^T/8 [mask]) @ V.
template<bool HAS_MASK>
__global__ __launch_bounds__(256, 4)
void attn_mfma_k(const __hip_bfloat16* __restrict__ Q, const __hip_bfloat16* __restrict__ K,
                 const __hip_bfloat16* __restrict__ V, const unsigned* __restrict__ mbits,
                 float* __restrict__ Xout) {
    int bid = blockIdx.x;
    int qt = bid & 31;            // 32 q-tiles
    int h  = (bid >> 5) & 7;
    int b  = bid >> 8;
    int q0 = qt * 64;
    int tid  = threadIdx.x;
    int w    = tid >> 6;          // wave 0..3
    int lane = tid & 63;
    int c    = lane & 15;         // n/col-in-tile (also m for A-frags)
    int quad = lane >> 4;         // 0..3

    __shared__ __hip_bfloat16 Kt[64 * 64];      // [key][dk] xor-swizzled 16B chunks
    __shared__ __hip_bfloat16 VT[64 * 72];      // [dk][key], pad 72
    __shared__ __hip_bfloat16 Ps[4 * 16 * 72];  // per-wave P [qrow][key], pad 72
    __hip_bfloat16* Psw = Ps + w * 16 * 72;

    // Q fragments in registers (A-layout: m=c, k=quad*8+j, two k-halves)
    const __hip_bfloat16* qrp = Q + ((size_t)(b*SEQ + q0 + 16*w + c)) * D_MODEL + h*DK;
    bf8_t qf0 = *(const bf8_t*)(qrp + quad*8);
    bf8_t qf1 = *(const bf8_t*)(qrp + 32 + quad*8);

    f4_t o[4];
    #pragma unroll
    for (int nt = 0; nt < 4; nt++) o[nt] = (f4_t){0.f,0.f,0.f,0.f};
    float m_r[4], l_r[4];
    #pragma unroll
    for (int r = 0; r < 4; r++) { m_r[r] = -INFINITY; l_r[r] = 0.f; }

    for (int kt = 0; kt < SEQ/64; kt++) {
        int k0 = kt * 64;
        __syncthreads();   // previous tile's LDS reads done before overwrite

        // --- stage K tile via global_load_lds (xor-swizzled chunk placement) ---
        const __hip_bfloat16* Kg = K + ((size_t)(b*SEQ + k0)) * D_MODEL + h*DK;
        #pragma unroll
        for (int i = 0; i < 2; i++) {
            int idx = i*256 + tid;
            int row = idx >> 3, c8 = idx & 7;
            const __hip_bfloat16* src = Kg + (size_t)row * D_MODEL + ((c8 ^ (row & 7)) * 8);
            GLD16(src, (char*)Kt + (size_t)(i*256 + w*64) * 16);
        }
        // --- stage V transposed: thread = 2 keys x 8 dk, pair-packed b32 writes ---
        {
            const __hip_bfloat16* Vg = V + ((size_t)(b*SEQ + k0)) * D_MODEL + h*DK;
            int key = (tid >> 3) * 2, d0 = (tid & 7) * 8;
            bf8_t v0 = *(const bf8_t*)(Vg + (size_t)key * D_MODEL + d0);
            bf8_t v1 = *(const bf8_t*)(Vg + (size_t)(key + 1) * D_MODEL + d0);
            #pragma unroll
            for (int j = 0; j < 8; j++) {
                unsigned pair = (unsigned)(unsigned short)v0[j]
                              | ((unsigned)(unsigned short)v1[j] << 16);
                *(unsigned*)&VT[(d0 + j) * 72 + key] = pair;
            }
        }
        __syncthreads();

        // --- S = Q K^T (per wave: 16 rows x 64 keys) ---
        f4_t sfr[4];
        #pragma unroll
        for (int nt = 0; nt < 4; nt++) {
            int row = nt*16 + c;
            int sw = row & 7;
            bf8_t k0f = *(const bf8_t*)&Kt[row*64 + ((quad ^ sw) * 8)];
            bf8_t k1f = *(const bf8_t*)&Kt[row*64 + (((4 + quad) ^ sw) * 8)];
            f4_t acc = (f4_t){0.f,0.f,0.f,0.f};
            acc = __builtin_amdgcn_mfma_f32_16x16x32_bf16(qf0, k0f, acc, 0, 0, 0);
            acc = __builtin_amdgcn_mfma_f32_16x16x32_bf16(qf1, k1f, acc, 0, 0, 0);
            sfr[nt] = acc;
        }

        // --- scale + mask ---
        unsigned mw0[4], mw1[4];
        if (HAS_MASK) {
            int mrow0 = b*SEQ + q0 + w*16 + quad*4;
            #pragma unroll
            for (int r = 0; r < 4; r++) {
                const unsigned* mp = mbits + (size_t)(mrow0 + r) * (SEQ/32) + (k0 >> 5);
                mw0[r] = mp[0]; mw1[r] = mp[1];
            }
        }
        #pragma unroll
        for (int nt = 0; nt < 4; nt++) {
            #pragma unroll
            for (int r = 0; r < 4; r++) {
                float s = sfr[nt][r] * 0.125f;
                if (HAS_MASK) {
                    unsigned wv = (nt < 2) ? mw0[r] : mw1[r];
                    int sh = (nt & 1) * 16 + c;
                    if (((wv >> sh) & 1u) == 0u) s = -1e9f;
                }
                sfr[nt][r] = s;
            }
        }

        // --- online softmax (row stats across 16 lanes of quad) ---
        float alpha[4];
        #pragma unroll
        for (int r = 0; r < 4; r++) {
            float mx = fmaxf(fmaxf(sfr[0][r], sfr[1][r]), fmaxf(sfr[2][r], sfr[3][r]));
            #pragma unroll
            for (int off = 1; off < 16; off <<= 1) mx = fmaxf(mx, __shfl_xor(mx, off));
            float mn = fmaxf(m_r[r], mx);
            alpha[r] = __expf(m_r[r] - mn);
            m_r[r] = mn;
        }
        #pragma unroll
        for (int r = 0; r < 4; r++) {
            float rs = 0.f;
            #pragma unroll
            for (int nt = 0; nt < 4; nt++) {
                float p = __expf(sfr[nt][r] - m_r[r]);
                sfr[nt][r] = p;
                rs += p;
            }
            #pragma unroll
            for (int off = 1; off < 16; off <<= 1) rs += __shfl_xor(rs, off);
            l_r[r] = l_r[r] * alpha[r] + rs;
            #pragma unroll
            for (int nt = 0; nt < 4; nt++) o[nt][r] *= alpha[r];
        }

        // --- P (C-layout) -> LDS bf16 [qrow][key] ---
        #pragma unroll
        for (int nt = 0; nt < 4; nt++)
            #pragma unroll
            for (int r = 0; r < 4; r++)
                ((short*)Psw)[(quad*4 + r) * 72 + nt*16 + c] = f2bf(sfr[nt][r]);

        // --- O += P V ---
        #pragma unroll
        for (int kh = 0; kh < 2; kh++) {
            bf8_t pf = *(const bf8_t*)&Psw[c*72 + kh*32 + quad*8];
            #pragma unroll
            for (int nt = 0; nt < 4; nt++) {
                bf8_t vf = *(const bf8_t*)&VT[(nt*16 + c) * 72 + kh*32 + quad*8];
                o[nt] = __builtin_amdgcn_mfma_f32_16x16x32_bf16(pf, vf, o[nt], 0, 0, 0);
            }
        }
    }

    // --- epilogue: residual add into fp32 X ---
    #pragma unroll
    for (int r = 0; r < 4; r++) {
        float il = 1.f / l_r[r];
        #pragma unroll
        for (int nt = 0; nt < 4; nt++) {
            size_t idx = ((size_t)(b*SEQ + q0 + w*16 + quad*4 + r)) * D_MODEL
                       + h*DK + nt*16 + c;
            Xout[idx] += o[nt][r] * il;
        }
    }
}

// ---------------- MFMA GEMM: C[M,N] = A[M,K] @ BT[N,K]^T + bias ----------------
// MODE 0: C bf16 = relu(acc+bias);  MODE 1: C fp32 += acc+bias (residual in C)
template<int MODE>
__global__ __launch_bounds__(256, 2)
void gemm_bf16_k(const __hip_bfloat16* __restrict__ A, const __hip_bfloat16* __restrict__ BT,
                 const void* __restrict__ bias, const int* __restrict__ flagp,
                 void* __restrict__ C, int Ksz, int Nsz) {
    int f32 = *flagp;
    __shared__ __hip_bfloat16 As[128 * 64];  // xor-swizzled chunks
    __shared__ __hip_bfloat16 Bs[128 * 64];
    int tid  = threadIdx.x;
    int w    = tid >> 6;
    int c    = tid & 15;          // lane&15 (lane = tid&63, c = lane&15)
    int quad = (tid >> 4) & 3;
    int wy = w >> 1, wx = w & 1;
    int r0 = blockIdx.y * 128, c0 = blockIdx.x * 128;

    f4_t acc[4][4];
    #pragma unroll
    for (int i = 0; i < 4; i++)
        #pragma unroll
        for (int j = 0; j < 4; j++) acc[i][j] = (f4_t){0.f,0.f,0.f,0.f};

    for (int k0 = 0; k0 < Ksz; k0 += 64) {
        __syncthreads();
        #pragma unroll
        for (int i = 0; i < 4; i++) {
            int idx = i*256 + tid;
            int row = idx >> 3, c8 = idx & 7;
            const __hip_bfloat16* srcA = A + (size_t)(r0 + row) * Ksz + k0 + ((c8 ^ (row & 7)) * 8);
            GLD16(srcA, (char*)As + (size_t)(i*256 + w*64) * 16);
            const __hip_bfloat16* srcB = BT + (size_t)(c0 + row) * Ksz + k0 + ((c8 ^ (row & 7)) * 8);
            GLD16(srcB, (char*)Bs + (size_t)(i*256 + w*64) * 16);
        }
        __syncthreads();

        #pragma unroll
        for (int kh = 0; kh < 2; kh++) {
            bf8_t af[4], bf[4];
            #pragma unroll
            for (int mt = 0; mt < 4; mt++) {
                int row = wy*64 + mt*16 + c;
                af[mt] = *(const bf8_t*)&As[row*64 + (((kh*4 + quad) ^ (row & 7)) * 8)];
            }
            #pragma unroll
            for (int nt = 0; nt < 4; nt++) {
                int row = wx*64 + nt*16 + c;
                bf[nt] = *(const bf8_t*)&Bs[row*64 + (((kh*4 + quad) ^ (row & 7)) * 8)];
            }
            #pragma unroll
            for (int mt = 0; mt < 4; mt++)
                #pragma unroll
                for (int nt = 0; nt < 4; nt++)
                    acc[mt][nt] = __builtin_amdgcn_mfma_f32_16x16x32_bf16(af[mt], bf[nt], acc[mt][nt], 0, 0, 0);
        }
    }

    #pragma unroll
    for (int mt = 0; mt < 4; mt++) {
        #pragma unroll
        for (int nt = 0; nt < 4; nt++) {
            int col = c0 + wx*64 + nt*16 + c;
            float bv = ldf(bias, col, f32);
            #pragma unroll
            for (int r = 0; r < 4; r++) {
                int m = r0 + wy*64 + mt*16 + quad*4 + r;
                float v = acc[mt][nt][r] + bv;
                if (MODE == 0) {
                    ((__hip_bfloat16*)C)[(size_t)m * Nsz + col] = __float2bfloat16(fmaxf(v, 0.f));
                } else {
                    ((float*)C)[(size_t)m * Nsz + col] += v;
                }
            }
        }
    }
}

// ---------------- launch ----------------
extern "C" void kernel_launch(void* const* d_in, const int* in_sizes, int n_in,
                              void* d_out, int out_size, void* d_ws, size_t ws_size,
                              hipStream_t stream) {
    const void* x    = d_in[0];
    const void* enc  = d_in[1];
    const int*  mask = (const int*)d_in[2];
    const void* ln1g = d_in[3];
    const void* ln1b = d_in[4];
    const void* ln2g = d_in[5];
    const void* ln2b = d_in[6];
    const void* ln3g = d_in[7];
    const void* ln3b = d_in[8];
    const void* W1   = d_in[9];
    const void* b1   = d_in[10];
    const void* W2   = d_in[11];
    const void* b2   = d_in[12];

    char* ws = (char*)d_ws;
    float*          bufX  = (float*)ws;                                // 16MB fp32 residual
    __hip_bfloat16* bufQ  = (__hip_bfloat16*)(ws + (16u<<20));         // 8MB LN out bf16
    __hip_bfloat16* bufE  = (__hip_bfloat16*)(ws + (24u<<20));         // 8MB encoder bf16
    __hip_bfloat16* bufH  = (__hip_bfloat16*)(ws + (32u<<20));         // 16MB FFN hidden bf16
    __hip_bfloat16* W1T   = (__hip_bfloat16*)(ws + (48u<<20));         // 1MB
    __hip_bfloat16* W2T   = (__hip_bfloat16*)(ws + (49u<<20));         // 1MB
    unsigned*       mbits = (unsigned*)(ws + (50u<<20));               // 2MB
    int*            flags = (int*)(ws + (52u<<20));

    dim3 blk(256);
    detect_k<<<1, blk, 0, stream>>>((const unsigned*)x, flags);
    cast_in_k<<<NELEM/256, blk, 0, stream>>>(x, flags, bufX, NELEM);
    cast_bf16_k<<<NELEM/256, blk, 0, stream>>>(enc, flags, bufE, NELEM);
    maskbits_k<<<NTOK/4, blk, 0, stream>>>(mask, mbits);
    transpose_k<<<dim3(D_FF/32, D_MODEL/32), blk, 0, stream>>>(W1, flags, W1T, D_MODEL, D_FF);
    transpose_k<<<dim3(D_MODEL/32, D_FF/32), blk, 0, stream>>>(W2, flags, W2T, D_FF, D_MODEL);

    // LN1 + masked self-attention + residual
    layernorm_k<<<NTOK/4, blk, 0, stream>>>(bufX, ln1g, ln1b, flags, bufQ);
    attn_mfma_k<true><<<BATCH*HEADS*(SEQ/64), blk, 0, stream>>>(bufQ, bufQ, bufQ, mbits, bufX);
    // LN2 + cross-attention + residual
    layernorm_k<<<NTOK/4, blk, 0, stream>>>(bufX, ln2g, ln2b, flags, bufQ);
    attn_mfma_k<false><<<BATCH*HEADS*(SEQ/64), blk, 0, stream>>>(bufQ, bufE, bufE, nullptr, bufX);
    // LN3 + FFN + residual
    layernorm_k<<<NTOK/4, blk, 0, stream>>>(bufX, ln3g, ln3b, flags, bufQ);
    gemm_bf16_k<0><<<dim3(D_FF/128, NTOK/128), blk, 0, stream>>>(bufQ, W1T, b1, flags, bufH, D_MODEL, D_FF);
    gemm_bf16_k<1><<<dim3(D_MODEL/128, NTOK/128), blk, 0, stream>>>(bufH, W2T, b2, flags, bufX, D_FF, D_MODEL);

    cast_out_k<<<NELEM/256, blk, 0, stream>>>(bufX, flags, d_out, NELEM);
}

// Round 4
// 463.775 us; speedup vs baseline: 7.5151x; 1.2604x over previous
//
#include <hip/hip_runtime.h>
#include <hip/hip_bf16.h>

#define D_MODEL 512
#define HEADS   8
#define DK      64
#define D_FF    1024
#define SEQ     2048
#define BATCH   4
#define NTOK    (BATCH*SEQ)          // 8192 rows
#define NELEM   (NTOK*D_MODEL)       // 4,194,304

#define QSCALE  0.18033688011112042f // 0.125 * log2(e)
#define MASKNEG -30000.0f

typedef __attribute__((ext_vector_type(8))) short bf8_t;   // 8 bf16 (4 VGPRs)
typedef __attribute__((ext_vector_type(4))) float f4_t;    // 4 fp32

#define GLD16(gp, lp) __builtin_amdgcn_global_load_lds( \
    (const __attribute__((address_space(1))) void*)(gp), \
    (__attribute__((address_space(3))) void*)(lp), 16, 0, 0)

__device__ __forceinline__ float ldf(const void* p, size_t i, int f32) {
    return f32 ? ((const float*)p)[i] : __bfloat162float(((const __hip_bfloat16*)p)[i]);
}
__device__ __forceinline__ short f2bf(float f) {
    union { __hip_bfloat16 h; short s; } u; u.h = __float2bfloat16(f); return u.s;
}
__device__ __forceinline__ float bf2f(short s) {
    return __uint_as_float(((unsigned)(unsigned short)s) << 16);
}
__device__ __forceinline__ unsigned fbits(float f) { return __float_as_uint(f); }

// ---------------- dtype detector (bf16 vs fp32 inputs) ----------------
__global__ void detect_k(const uint4* __restrict__ w, int* __restrict__ flags) {
    __shared__ int found;
    if (threadIdx.x == 0) found = 0;
    __syncthreads();
    int hit = 0;
    for (int i = threadIdx.x; i < 4096; i += 256) {   // 16384 words
        uint4 u = w[i];
        if (((u.x & 0x7F80u) == 0x7F80u) || ((u.y & 0x7F80u) == 0x7F80u) ||
            ((u.z & 0x7F80u) == 0x7F80u) || ((u.w & 0x7F80u) == 0x7F80u)) hit = 1;
    }
    if (hit) atomicOr(&found, 1);
    __syncthreads();
    if (threadIdx.x == 0) flags[0] = found ? 1 : 0;
}

// ---------------- enc cast ----------------
__global__ void cast_bf16_k(const void* __restrict__ in, const int* __restrict__ flagp,
                            __hip_bfloat16* __restrict__ out, int n) {
    int f32 = *flagp;
    int i = blockIdx.x * blockDim.x + threadIdx.x;
    if (i < n) out[i] = __float2bfloat16(ldf(in, i, f32));
}

// ---------------- mask -> bitmask (64MB int32 -> 2MB bits) ----------------
__global__ __launch_bounds__(256)
void maskbits_k(const int* __restrict__ mask, unsigned* __restrict__ mb) {
    int row  = blockIdx.x * 4 + (threadIdx.x >> 6);
    int lane = threadIdx.x & 63;
    const int* mr = mask + (size_t)row * SEQ;
    for (int it = 0; it < SEQ/64; it++) {
        unsigned long long bal = __ballot(mr[it*64 + lane] != 0);
        if (lane == 0)  mb[(size_t)row*(SEQ/32) + it*2]     = (unsigned)bal;
        if (lane == 32) mb[(size_t)row*(SEQ/32) + it*2 + 1] = (unsigned)(bal >> 32);
    }
}

// ---------------- LN1 fused with input cast: x(flag) -> bufX fp32 + bufQ bf16 ----------------
__global__ __launch_bounds__(256)
void ln_first_k(const void* __restrict__ x, const void* __restrict__ g,
                const void* __restrict__ b, const int* __restrict__ flagp,
                float* __restrict__ xout, __hip_bfloat16* __restrict__ y) {
    int f32  = *flagp;
    int row  = blockIdx.x * 4 + (threadIdx.x >> 6);
    int lane = threadIdx.x & 63;
    size_t base = (size_t)row * D_MODEL;
    float v[8];
    float s = 0.f;
    #pragma unroll
    for (int i = 0; i < 8; i++) { v[i] = ldf(x, base + lane + i*64, f32); s += v[i]; }
    #pragma unroll
    for (int off = 32; off; off >>= 1) s += __shfl_xor(s, off);
    float mu = s * (1.f / D_MODEL);
    float ss = 0.f;
    #pragma unroll
    for (int i = 0; i < 8; i++) { float d = v[i] - mu; ss += d * d; }
    #pragma unroll
    for (int off = 32; off; off >>= 1) ss += __shfl_xor(ss, off);
    float rstd = rsqrtf(ss * (1.f / D_MODEL) + 1e-5f);
    #pragma unroll
    for (int i = 0; i < 8; i++) {
        int c = lane + i*64;
        xout[base + c] = v[i];
        y[base + c] = __float2bfloat16((v[i] - mu) * rstd * ldf(g, c, f32) + ldf(b, c, f32));
    }
}

// ---------------- layernorm (fp32 in, bf16 out) ----------------
__global__ __launch_bounds__(256)
void layernorm_k(const float* __restrict__ x, const void* __restrict__ g,
                 const void* __restrict__ b, const int* __restrict__ flagp,
                 __hip_bfloat16* __restrict__ y) {
    int f32  = *flagp;
    int row  = blockIdx.x * 4 + (threadIdx.x >> 6);
    int lane = threadIdx.x & 63;
    const float* xr = x + (size_t)row * D_MODEL;
    float v[8];
    float s = 0.f;
    #pragma unroll
    for (int i = 0; i < 8; i++) { v[i] = xr[lane + i*64]; s += v[i]; }
    #pragma unroll
    for (int off = 32; off; off >>= 1) s += __shfl_xor(s, off);
    float mu = s * (1.f / D_MODEL);
    float ss = 0.f;
    #pragma unroll
    for (int i = 0; i < 8; i++) { float d = v[i] - mu; ss += d * d; }
    #pragma unroll
    for (int off = 32; off; off >>= 1) ss += __shfl_xor(ss, off);
    float rstd = rsqrtf(ss * (1.f / D_MODEL) + 1e-5f);
    __hip_bfloat16* yr = y + (size_t)row * D_MODEL;
    #pragma unroll
    for (int i = 0; i < 8; i++) {
        int c = lane + i*64;
        yr[c] = __float2bfloat16((v[i] - mu) * rstd * ldf(g, c, f32) + ldf(b, c, f32));
    }
}

// ---------------- transpose (+cast) weights: dst[N][K] = src[K][N] ----------------
__global__ __launch_bounds__(256)
void transpose_k(const void* __restrict__ src, const int* __restrict__ flagp,
                 __hip_bfloat16* __restrict__ dst, int K, int N) {
    int f32 = *flagp;
    __shared__ __hip_bfloat16 t[32][33];
    int bx = blockIdx.x * 32, by = blockIdx.y * 32;
    int tx = threadIdx.x & 31, ty = threadIdx.x >> 5;
    #pragma unroll
    for (int j = 0; j < 32; j += 8) {
        int k = by + ty + j, n = bx + tx;
        t[ty + j][tx] = __float2bfloat16(ldf(src, (size_t)k * N + n, f32));
    }
    __syncthreads();
    #pragma unroll
    for (int j = 0; j < 32; j += 8) {
        int n = bx + ty + j, k = by + tx;
        dst[(size_t)n * K + k] = t[tx][ty + j];
    }
}

__device__ __forceinline__ bf8_t prescale_q(bf8_t q) {
    bf8_t r;
    #pragma unroll
    for (int j = 0; j < 8; j++) r[j] = f2bf(bf2f(q[j]) * QSCALE);
    return r;
}

// ---------------- MFMA flash attention, S^T formulation ----------------
// Block: 64 q of one (b,h); 4 waves x 16 q. K-tiles of 64 keys.
// S^T = K·Q^T (A=K-frag, B=Q-frag). Per-lane softmax stats (query = lane&15).
// P^T built in-register via bpermute -> B-operand of O^T = V^T·P^T.
template<bool HAS_MASK>
__global__ __launch_bounds__(256, 4)
void attn_mfma_k(const __hip_bfloat16* __restrict__ Q, const __hip_bfloat16* __restrict__ K,
                 const __hip_bfloat16* __restrict__ V, const unsigned* __restrict__ mbits,
                 float* __restrict__ Xout) {
    int bid = blockIdx.x;
    int qt = bid & 31;
    int h  = (bid >> 5) & 7;
    int b  = bid >> 8;
    int q0 = qt * 64;
    int tid  = threadIdx.x;
    int w    = tid >> 6;
    int lane = tid & 63;
    int c    = lane & 15;         // query (n), also m-index for A-frag rows
    int quad = lane >> 4;

    __shared__ __hip_bfloat16 Kt[64 * 64];   // [key][dk], 8-chunk XOR by key&7
    __shared__ __hip_bfloat16 VT[64 * 64];   // [dk][key], 8-chunk XOR by dk&7

    // Q fragments (B-operand), prescaled by 0.125*log2e
    const __hip_bfloat16* qrp = Q + ((size_t)(b*SEQ + q0 + 16*w + c)) * D_MODEL + h*DK;
    bf8_t qf0 = prescale_q(*(const bf8_t*)(qrp + quad*8));
    bf8_t qf1 = prescale_q(*(const bf8_t*)(qrp + 32 + quad*8));

    // kt-invariant LDS read pointers
    const bf8_t* kp[4][2];
    const bf8_t* vp[4][2];
    #pragma unroll
    for (int t = 0; t < 4; t++)
        #pragma unroll
        for (int kh = 0; kh < 2; kh++) {
            int off = (16*t + c)*64 + (((4*kh + quad) ^ (c & 7)) * 8);
            kp[t][kh] = (const bf8_t*)&Kt[off];
            vp[t][kh] = (const bf8_t*)&VT[off];
        }

    // VT staging: this thread owns keys (key0,key0+1) x dk [d0,d0+8)
    int key0 = (tid >> 3) * 2, d0 = (tid & 7) * 8;
    unsigned* vtw[8];
    #pragma unroll
    for (int j = 0; j < 8; j++)
        vtw[j] = (unsigned*)VT + (d0 + j)*32 + (((key0 >> 3) ^ j) * 4) + ((key0 & 7) >> 1);

    // Kt staging src params (2 GLD16 per thread)
    int krow[2], kc8[2];
    #pragma unroll
    for (int i = 0; i < 2; i++) {
        int idx = i*256 + tid;
        krow[i] = idx >> 3;
        kc8[i]  = ((idx & 7) ^ (krow[i] & 7)) * 8;
    }

    const unsigned* mrow_p = nullptr;
    if (HAS_MASK) mrow_p = mbits + (size_t)(b*SEQ + q0 + 16*w + c) * (SEQ/32);
    int qsh = quad * 4;

    f4_t o[4];
    #pragma unroll
    for (int mt = 0; mt < 4; mt++) o[mt] = (f4_t){0.f,0.f,0.f,0.f};
    float m_ = -INFINITY, l_ = 0.f;
    int srcA = c + 32*(quad & 1), srcB = srcA + 16;
    bool hiQ = quad >= 2;

    for (int kt = 0; kt < SEQ/64; kt++) {
        int k0 = kt * 64;
        __syncthreads();
        // stage K
        const __hip_bfloat16* Kg = K + ((size_t)(b*SEQ + k0)) * D_MODEL + h*DK;
        GLD16(Kg + (size_t)krow[0]*D_MODEL + kc8[0], (char*)Kt + (size_t)(w*64) * 16);
        GLD16(Kg + (size_t)krow[1]*D_MODEL + kc8[1], (char*)Kt + (size_t)(256 + w*64) * 16);
        // stage V transposed (pair-packed b32, XOR-chunked: <=2-way banks)
        {
            const __hip_bfloat16* Vg = V + ((size_t)(b*SEQ + k0 + key0)) * D_MODEL + h*DK + d0;
            bf8_t v0 = *(const bf8_t*)Vg;
            bf8_t v1 = *(const bf8_t*)(Vg + D_MODEL);
            const unsigned* v0u = (const unsigned*)&v0;
            const unsigned* v1u = (const unsigned*)&v1;
            #pragma unroll
            for (int dw = 0; dw < 4; dw++) {
                *vtw[2*dw]     = __builtin_amdgcn_perm(v1u[dw], v0u[dw], 0x05040100u);
                *vtw[2*dw + 1] = __builtin_amdgcn_perm(v1u[dw], v0u[dw], 0x07060302u);
            }
        }
        __syncthreads();

        // --- S^T = K Q^T : per wave 64 keys x 16 queries ---
        f4_t sfr[4];
        #pragma unroll
        for (int nt = 0; nt < 4; nt++) {
            f4_t acc = (f4_t){0.f,0.f,0.f,0.f};
            acc = __builtin_amdgcn_mfma_f32_16x16x32_bf16(*kp[nt][0], qf0, acc, 0, 0, 0);
            acc = __builtin_amdgcn_mfma_f32_16x16x32_bf16(*kp[nt][1], qf1, acc, 0, 0, 0);
            sfr[nt] = acc;
        }

        // --- mask + in-lane max ---
        unsigned w0 = 0, w1 = 0;
        if (HAS_MASK) {
            uint2 mw = *(const uint2*)(mrow_p + kt*2);
            w0 = mw.x >> qsh; w1 = mw.y >> qsh;
        }
        float mx = -INFINITY;
        #pragma unroll
        for (int nt = 0; nt < 4; nt++) {
            #pragma unroll
            for (int r = 0; r < 4; r++) {
                float s = sfr[nt][r];
                if (HAS_MASK) {
                    unsigned sel = (nt < 2) ? w0 : w1;
                    s = ((sel >> ((nt & 1)*16 + r)) & 1u) ? s : MASKNEG;
                    sfr[nt][r] = s;
                }
                mx = fmaxf(mx, s);
            }
        }
        mx = fmaxf(mx, __shfl_xor(mx, 16));
        mx = fmaxf(mx, __shfl_xor(mx, 32));
        float mn = fmaxf(m_, mx);
        float alpha = exp2f(m_ - mn);
        m_ = mn;

        float rs = 0.f;
        #pragma unroll
        for (int nt = 0; nt < 4; nt++)
            #pragma unroll
            for (int r = 0; r < 4; r++) {
                float p = exp2f(sfr[nt][r] - mn);
                sfr[nt][r] = p;
                rs += p;
            }
        rs += __shfl_xor(rs, 16);
        rs += __shfl_xor(rs, 32);
        l_ = l_ * alpha + rs;
        #pragma unroll
        for (int mt = 0; mt < 4; mt++) o[mt] *= alpha;

        // --- pack P^T to bf16 pairs (truncation via v_perm) ---
        unsigned pk0[4], pk1[4];
        #pragma unroll
        for (int nt = 0; nt < 4; nt++) {
            pk0[nt] = __builtin_amdgcn_perm(fbits(sfr[nt][1]), fbits(sfr[nt][0]), 0x07060302u);
            pk1[nt] = __builtin_amdgcn_perm(fbits(sfr[nt][3]), fbits(sfr[nt][2]), 0x07060302u);
        }

        // --- O^T += V^T P^T ---
        #pragma unroll
        for (int kh = 0; kh < 2; kh++) {
            unsigned a00 = (unsigned)__shfl((int)pk0[2*kh],     srcA);
            unsigned a01 = (unsigned)__shfl((int)pk0[2*kh + 1], srcA);
            unsigned a10 = (unsigned)__shfl((int)pk1[2*kh],     srcA);
            unsigned a11 = (unsigned)__shfl((int)pk1[2*kh + 1], srcA);
            unsigned b00 = (unsigned)__shfl((int)pk0[2*kh],     srcB);
            unsigned b01 = (unsigned)__shfl((int)pk0[2*kh + 1], srcB);
            unsigned b10 = (unsigned)__shfl((int)pk1[2*kh],     srcB);
            unsigned b11 = (unsigned)__shfl((int)pk1[2*kh + 1], srcB);
            union { bf8_t v; unsigned u[4]; } pf;
            pf.u[0] = hiQ ? a01 : a00;
            pf.u[1] = hiQ ? a11 : a10;
            pf.u[2] = hiQ ? b01 : b00;
            pf.u[3] = hiQ ? b11 : b10;
            #pragma unroll
            for (int mt = 0; mt < 4; mt++)
                o[mt] = __builtin_amdgcn_mfma_f32_16x16x32_bf16(*vp[mt][kh], pf.v, o[mt], 0, 0, 0);
        }
    }

    // --- epilogue: O[q][d] += ; o[mt] holds O^T tile: row=d=quad*4+r, col=q=c ---
    float il = 1.f / l_;
    size_t rb = ((size_t)(b*SEQ + q0 + 16*w + c)) * D_MODEL + h*DK;
    #pragma unroll
    for (int mt = 0; mt < 4; mt++)
        #pragma unroll
        for (int r = 0; r < 4; r++)
            Xout[rb + 16*mt + quad*4 + r] += o[mt][r] * il;
}

// ---------------- MFMA GEMM1: bufH = relu(A @ W1T^T + b1), bf16 out ----------------
__global__ __launch_bounds__(256, 2)
void gemm_relu_k(const __hip_bfloat16* __restrict__ A, const __hip_bfloat16* __restrict__ BT,
                 const void* __restrict__ bias, const int* __restrict__ flagp,
                 __hip_bfloat16* __restrict__ C, int Ksz, int Nsz) {
    int f32 = *flagp;
    __shared__ __hip_bfloat16 As[128 * 64];
    __shared__ __hip_bfloat16 Bs[128 * 64];
    int tid  = threadIdx.x;
    int w    = tid >> 6;
    int c    = tid & 15;
    int quad = (tid >> 4) & 3;
    int wy = w >> 1, wx = w & 1;
    int r0 = blockIdx.y * 128, c0 = blockIdx.x * 128;

    f4_t acc[4][4];
    #pragma unroll
    for (int i = 0; i < 4; i++)
        #pragma unroll
        for (int j = 0; j < 4; j++) acc[i][j] = (f4_t){0.f,0.f,0.f,0.f};

    for (int k0 = 0; k0 < Ksz; k0 += 64) {
        __syncthreads();
        #pragma unroll
        for (int i = 0; i < 4; i++) {
            int idx = i*256 + tid;
            int row = idx >> 3, c8 = idx & 7;
            GLD16(A  + (size_t)(r0 + row) * Ksz + k0 + ((c8 ^ (row & 7)) * 8),
                  (char*)As + (size_t)(i*256 + w*64) * 16);
            GLD16(BT + (size_t)(c0 + row) * Ksz + k0 + ((c8 ^ (row & 7)) * 8),
                  (char*)Bs + (size_t)(i*256 + w*64) * 16);
        }
        __syncthreads();

        #pragma unroll
        for (int kh = 0; kh < 2; kh++) {
            bf8_t af[4], bf[4];
            #pragma unroll
            for (int mt = 0; mt < 4; mt++) {
                int row = wy*64 + mt*16 + c;
                af[mt] = *(const bf8_t*)&As[row*64 + (((kh*4 + quad) ^ (row & 7)) * 8)];
            }
            #pragma unroll
            for (int nt = 0; nt < 4; nt++) {
                int row = wx*64 + nt*16 + c;
                bf[nt] = *(const bf8_t*)&Bs[row*64 + (((kh*4 + quad) ^ (row & 7)) * 8)];
            }
            #pragma unroll
            for (int mt = 0; mt < 4; mt++)
                #pragma unroll
                for (int nt = 0; nt < 4; nt++)
                    acc[mt][nt] = __builtin_amdgcn_mfma_f32_16x16x32_bf16(af[mt], bf[nt], acc[mt][nt], 0, 0, 0);
        }
    }

    #pragma unroll
    for (int mt = 0; mt < 4; mt++)
        #pragma unroll
        for (int nt = 0; nt < 4; nt++) {
            int col = c0 + wx*64 + nt*16 + c;
            float bv = ldf(bias, col, f32);
            #pragma unroll
            for (int r = 0; r < 4; r++) {
                int m = r0 + wy*64 + mt*16 + quad*4 + r;
                C[(size_t)m * Nsz + col] = __float2bfloat16(fmaxf(acc[mt][nt][r] + bv, 0.f));
            }
        }
}

// ---------------- MFMA GEMM2: out = resid + A @ W2T^T + b2 (flagged dtype out) ----------------
__global__ __launch_bounds__(256, 2)
void gemm_out_k(const __hip_bfloat16* __restrict__ A, const __hip_bfloat16* __restrict__ BT,
                const void* __restrict__ bias, const float* __restrict__ resid,
                const int* __restrict__ flagp, void* __restrict__ out, int Ksz, int Nsz) {
    int f32 = *flagp;
    __shared__ __hip_bfloat16 As[128 * 64];
    __shared__ __hip_bfloat16 Bs[128 * 64];
    int tid  = threadIdx.x;
    int w    = tid >> 6;
    int c    = tid & 15;
    int quad = (tid >> 4) & 3;
    int wy = w >> 1, wx = w & 1;
    int r0 = blockIdx.y * 128, c0 = blockIdx.x * 128;

    f4_t acc[4][4];
    #pragma unroll
    for (int i = 0; i < 4; i++)
        #pragma unroll
        for (int j = 0; j < 4; j++) acc[i][j] = (f4_t){0.f,0.f,0.f,0.f};

    for (int k0 = 0; k0 < Ksz; k0 += 64) {
        __syncthreads();
        #pragma unroll
        for (int i = 0; i < 4; i++) {
            int idx = i*256 + tid;
            int row = idx >> 3, c8 = idx & 7;
            GLD16(A  + (size_t)(r0 + row) * Ksz + k0 + ((c8 ^ (row & 7)) * 8),
                  (char*)As + (size_t)(i*256 + w*64) * 16);
            GLD16(BT + (size_t)(c0 + row) * Ksz + k0 + ((c8 ^ (row & 7)) * 8),
                  (char*)Bs + (size_t)(i*256 + w*64) * 16);
        }
        __syncthreads();

        #pragma unroll
        for (int kh = 0; kh < 2; kh++) {
            bf8_t af[4], bf[4];
            #pragma unroll
            for (int mt = 0; mt < 4; mt++) {
                int row = wy*64 + mt*16 + c;
                af[mt] = *(const bf8_t*)&As[row*64 + (((kh*4 + quad) ^ (row & 7)) * 8)];
            }
            #pragma unroll
            for (int nt = 0; nt < 4; nt++) {
                int row = wx*64 + nt*16 + c;
                bf[nt] = *(const bf8_t*)&Bs[row*64 + (((kh*4 + quad) ^ (row & 7)) * 8)];
            }
            #pragma unroll
            for (int mt = 0; mt < 4; mt++)
                #pragma unroll
                for (int nt = 0; nt < 4; nt++)
                    acc[mt][nt] = __builtin_amdgcn_mfma_f32_16x16x32_bf16(af[mt], bf[nt], acc[mt][nt], 0, 0, 0);
        }
    }

    #pragma unroll
    for (int mt = 0; mt < 4; mt++)
        #pragma unroll
        for (int nt = 0; nt < 4; nt++) {
            int col = c0 + wx*64 + nt*16 + c;
            float bv = ldf(bias, col, f32);
            #pragma unroll
            for (int r = 0; r < 4; r++) {
                int m = r0 + wy*64 + mt*16 + quad*4 + r;
                float v = acc[mt][nt][r] + bv + resid[(size_t)m * Nsz + col];
                if (f32) ((float*)out)[(size_t)m * Nsz + col] = v;
                else     ((__hip_bfloat16*)out)[(size_t)m * Nsz + col] = __float2bfloat16(v);
            }
        }
}

// ---------------- launch ----------------
extern "C" void kernel_launch(void* const* d_in, const int* in_sizes, int n_in,
                              void* d_out, int out_size, void* d_ws, size_t ws_size,
                              hipStream_t stream) {
    const void* x    = d_in[0];
    const void* enc  = d_in[1];
    const int*  mask = (const int*)d_in[2];
    const void* ln1g = d_in[3];
    const void* ln1b = d_in[4];
    const void* ln2g = d_in[5];
    const void* ln2b = d_in[6];
    const void* ln3g = d_in[7];
    const void* ln3b = d_in[8];
    const void* W1   = d_in[9];
    const void* b1   = d_in[10];
    const void* W2   = d_in[11];
    const void* b2   = d_in[12];

    char* ws = (char*)d_ws;
    float*          bufX  = (float*)ws;                                // 16MB fp32 residual
    __hip_bfloat16* bufQ  = (__hip_bfloat16*)(ws + (16u<<20));         // 8MB LN out bf16
    __hip_bfloat16* bufE  = (__hip_bfloat16*)(ws + (24u<<20));         // 8MB encoder bf16
    __hip_bfloat16* bufH  = (__hip_bfloat16*)(ws + (32u<<20));         // 16MB FFN hidden bf16
    __hip_bfloat16* W1T   = (__hip_bfloat16*)(ws + (48u<<20));         // 1MB
    __hip_bfloat16* W2T   = (__hip_bfloat16*)(ws + (49u<<20));         // 1MB
    unsigned*       mbits = (unsigned*)(ws + (50u<<20));               // 2MB
    int*            flags = (int*)(ws + (52u<<20));

    dim3 blk(256);
    detect_k<<<1, blk, 0, stream>>>((const uint4*)x, flags);
    maskbits_k<<<NTOK/4, blk, 0, stream>>>(mask, mbits);
    cast_bf16_k<<<NELEM/256, blk, 0, stream>>>(enc, flags, bufE, NELEM);
    transpose_k<<<dim3(D_FF/32, D_MODEL/32), blk, 0, stream>>>(W1, flags, W1T, D_MODEL, D_FF);
    transpose_k<<<dim3(D_MODEL/32, D_FF/32), blk, 0, stream>>>(W2, flags, W2T, D_FF, D_MODEL);

    // LN1 (fused input cast) + masked self-attention + residual
    ln_first_k<<<NTOK/4, blk, 0, stream>>>(x, ln1g, ln1b, flags, bufX, bufQ);
    attn_mfma_k<true><<<BATCH*HEADS*(SEQ/64), blk, 0, stream>>>(bufQ, bufQ, bufQ, mbits, bufX);
    // LN2 + cross-attention + residual
    layernorm_k<<<NTOK/4, blk, 0, stream>>>(bufX, ln2g, ln2b, flags, bufQ);
    attn_mfma_k<false><<<BATCH*HEADS*(SEQ/64), blk, 0, stream>>>(bufQ, bufE, bufE, nullptr, bufX);
    // LN3 + FFN + residual (+final cast fused into GEMM2)
    layernorm_k<<<NTOK/4, blk, 0, stream>>>(bufX, ln3g, ln3b, flags, bufQ);
    gemm_relu_k<<<dim3(D_FF/128, NTOK/128), blk, 0, stream>>>(bufQ, W1T, b1, flags, bufH, D_MODEL, D_FF);
    gemm_out_k<<<dim3(D_MODEL/128, NTOK/128), blk, 0, stream>>>(bufH, W2T, b2, bufX, flags, d_out, D_FF, D_MODEL);
}

// Round 5
// 434.514 us; speedup vs baseline: 8.0211x; 1.0673x over previous
//
#include <hip/hip_runtime.h>
#include <hip/hip_bf16.h>

#define D_MODEL 512
#define HEADS   8
#define DK      64
#define D_FF    1024
#define SEQ     2048
#define BATCH   4
#define NTOK    (BATCH*SEQ)          // 8192 rows
#define NELEM   (NTOK*D_MODEL)       // 4,194,304

#define QSCALE  0.18033688011112042f // 0.125 * log2(e)

typedef __attribute__((ext_vector_type(8))) short bf8_t;   // 8 bf16 (4 VGPRs)
typedef __attribute__((ext_vector_type(4))) float f4_t;    // 4 fp32

#define GLD16(gp, lp) __builtin_amdgcn_global_load_lds( \
    (const __attribute__((address_space(1))) void*)(gp), \
    (__attribute__((address_space(3))) void*)(lp), 16, 0, 0)

__device__ __forceinline__ float ldf(const void* p, size_t i, int f32) {
    return f32 ? ((const float*)p)[i] : __bfloat162float(((const __hip_bfloat16*)p)[i]);
}
__device__ __forceinline__ short f2bf(float f) {
    union { __hip_bfloat16 h; short s; } u; u.h = __float2bfloat16(f); return u.s;
}
__device__ __forceinline__ float bf2f(short s) {
    return __uint_as_float(((unsigned)(unsigned short)s) << 16);
}
__device__ __forceinline__ unsigned fbits(float f) { return __float_as_uint(f); }

// ---------------- dtype detector (bf16 vs fp32 inputs) ----------------
__global__ void detect_k(const uint4* __restrict__ w, int* __restrict__ flags) {
    __shared__ int found;
    if (threadIdx.x == 0) found = 0;
    __syncthreads();
    int hit = 0;
    for (int i = threadIdx.x; i < 4096; i += 256) {
        uint4 u = w[i];
        if (((u.x & 0x7F80u) == 0x7F80u) || ((u.y & 0x7F80u) == 0x7F80u) ||
            ((u.z & 0x7F80u) == 0x7F80u) || ((u.w & 0x7F80u) == 0x7F80u)) hit = 1;
    }
    if (hit) atomicOr(&found, 1);
    __syncthreads();
    if (threadIdx.x == 0) flags[0] = found ? 1 : 0;
}

// ---------------- enc cast ----------------
__global__ void cast_bf16_k(const void* __restrict__ in, const int* __restrict__ flagp,
                            __hip_bfloat16* __restrict__ out, int n) {
    int f32 = *flagp;
    int i = blockIdx.x * blockDim.x + threadIdx.x;
    if (i < n) out[i] = __float2bfloat16(ldf(in, i, f32));
}

// ---------------- mask -> bitmask (64MB int32 -> 2MB bits) ----------------
__global__ __launch_bounds__(256)
void maskbits_k(const int* __restrict__ mask, unsigned* __restrict__ mb) {
    int row  = blockIdx.x * 4 + (threadIdx.x >> 6);
    int lane = threadIdx.x & 63;
    const int* mr = mask + (size_t)row * SEQ;
    for (int it = 0; it < SEQ/64; it++) {
        unsigned long long bal = __ballot(mr[it*64 + lane] != 0);
        if (lane == 0)  mb[(size_t)row*(SEQ/32) + it*2]     = (unsigned)bal;
        if (lane == 32) mb[(size_t)row*(SEQ/32) + it*2 + 1] = (unsigned)(bal >> 32);
    }
}

// ---------------- LN1 fused with input cast ----------------
__global__ __launch_bounds__(256)
void ln_first_k(const void* __restrict__ x, const void* __restrict__ g,
                const void* __restrict__ b, const int* __restrict__ flagp,
                float* __restrict__ xout, __hip_bfloat16* __restrict__ y) {
    int f32  = *flagp;
    int row  = blockIdx.x * 4 + (threadIdx.x >> 6);
    int lane = threadIdx.x & 63;
    size_t base = (size_t)row * D_MODEL;
    float v[8];
    float s = 0.f;
    #pragma unroll
    for (int i = 0; i < 8; i++) { v[i] = ldf(x, base + lane + i*64, f32); s += v[i]; }
    #pragma unroll
    for (int off = 32; off; off >>= 1) s += __shfl_xor(s, off);
    float mu = s * (1.f / D_MODEL);
    float ss = 0.f;
    #pragma unroll
    for (int i = 0; i < 8; i++) { float d = v[i] - mu; ss += d * d; }
    #pragma unroll
    for (int off = 32; off; off >>= 1) ss += __shfl_xor(ss, off);
    float rstd = rsqrtf(ss * (1.f / D_MODEL) + 1e-5f);
    #pragma unroll
    for (int i = 0; i < 8; i++) {
        int c = lane + i*64;
        xout[base + c] = v[i];
        y[base + c] = __float2bfloat16((v[i] - mu) * rstd * ldf(g, c, f32) + ldf(b, c, f32));
    }
}

// ---------------- layernorm (fp32 in, bf16 out) ----------------
__global__ __launch_bounds__(256)
void layernorm_k(const float* __restrict__ x, const void* __restrict__ g,
                 const void* __restrict__ b, const int* __restrict__ flagp,
                 __hip_bfloat16* __restrict__ y) {
    int f32  = *flagp;
    int row  = blockIdx.x * 4 + (threadIdx.x >> 6);
    int lane = threadIdx.x & 63;
    const float* xr = x + (size_t)row * D_MODEL;
    float v[8];
    float s = 0.f;
    #pragma unroll
    for (int i = 0; i < 8; i++) { v[i] = xr[lane + i*64]; s += v[i]; }
    #pragma unroll
    for (int off = 32; off; off >>= 1) s += __shfl_xor(s, off);
    float mu = s * (1.f / D_MODEL);
    float ss = 0.f;
    #pragma unroll
    for (int i = 0; i < 8; i++) { float d = v[i] - mu; ss += d * d; }
    #pragma unroll
    for (int off = 32; off; off >>= 1) ss += __shfl_xor(ss, off);
    float rstd = rsqrtf(ss * (1.f / D_MODEL) + 1e-5f);
    __hip_bfloat16* yr = y + (size_t)row * D_MODEL;
    #pragma unroll
    for (int i = 0; i < 8; i++) {
        int c = lane + i*64;
        yr[c] = __float2bfloat16((v[i] - mu) * rstd * ldf(g, c, f32) + ldf(b, c, f32));
    }
}

// ---------------- transpose (+cast) weights: dst[N][K] = src[K][N] ----------------
__global__ __launch_bounds__(256)
void transpose_k(const void* __restrict__ src, const int* __restrict__ flagp,
                 __hip_bfloat16* __restrict__ dst, int K, int N) {
    int f32 = *flagp;
    __shared__ __hip_bfloat16 t[32][33];
    int bx = blockIdx.x * 32, by = blockIdx.y * 32;
    int tx = threadIdx.x & 31, ty = threadIdx.x >> 5;
    #pragma unroll
    for (int j = 0; j < 32; j += 8) {
        int k = by + ty + j, n = bx + tx;
        t[ty + j][tx] = __float2bfloat16(ldf(src, (size_t)k * N + n, f32));
    }
    __syncthreads();
    #pragma unroll
    for (int j = 0; j < 32; j += 8) {
        int n = bx + ty + j, k = by + tx;
        dst[(size_t)n * K + k] = t[tx][ty + j];
    }
}

__device__ __forceinline__ bf8_t prescale_q(bf8_t q) {
    bf8_t r;
    #pragma unroll
    for (int j = 0; j < 8; j++) r[j] = f2bf(bf2f(q[j]) * QSCALE);
    return r;
}

// ---------------- MFMA flash attention, S^T formulation, 2 q-groups/wave ----------------
// Block: 128 q of one (b,h); 4 waves x 32 q (2 groups of 16). K-tiles of 64 keys.
// S^T = K·Q^T; per-lane softmax stats (query = lane&15, per group).
// P^T goes through a per-wave XOR-swizzled LDS buffer (write b64 / read b128, conflict-free).
template<bool HAS_MASK>
__global__ __launch_bounds__(256, 2)
void attn_mfma_k(const __hip_bfloat16* __restrict__ Q, const __hip_bfloat16* __restrict__ K,
                 const __hip_bfloat16* __restrict__ V, const unsigned* __restrict__ mbits,
                 float* __restrict__ Xout) {
    int bid = blockIdx.x;
    int qt = bid & 15;            // 2048/128 = 16 q-tiles
    int h  = (bid >> 4) & 7;
    int b  = bid >> 7;
    int q0 = qt * 128;
    int tid  = threadIdx.x;
    int w    = tid >> 6;
    int lane = tid & 63;
    int c    = lane & 15;
    int quad = lane >> 4;

    __shared__ __hip_bfloat16 Kt[64 * 64];        // [key][dk], chunk XOR by key&7
    __shared__ __hip_bfloat16 VT[64 * 64];        // [dk][key], chunk XOR by (dk&7)^((dk>>3)&7)
    __shared__ __hip_bfloat16 Pb[4][2][16 * 64];  // per-wave per-group P^T [q][key], XOR by q&7

    // Q fragments (B-operand), prescaled by 0.125*log2e
    bf8_t qf[2][2];
    #pragma unroll
    for (int g = 0; g < 2; g++) {
        const __hip_bfloat16* qrp = Q + ((size_t)(b*SEQ + q0 + 32*w + 16*g + c)) * D_MODEL + h*DK;
        qf[g][0] = prescale_q(*(const bf8_t*)(qrp + quad*8));
        qf[g][1] = prescale_q(*(const bf8_t*)(qrp + 32 + quad*8));
    }

    // kt-invariant LDS read pointers
    const bf8_t* kp[4][2];
    const bf8_t* vp[4][2];
    #pragma unroll
    for (int t = 0; t < 4; t++)
        #pragma unroll
        for (int kh = 0; kh < 2; kh++) {
            int row = 16*t + c;
            kp[t][kh] = (const bf8_t*)&Kt[row*64 + (((4*kh + quad) ^ (row & 7)) * 8)];
            vp[t][kh] = (const bf8_t*)&VT[row*64 + (((4*kh + quad) ^ (row & 7) ^ ((row >> 3) & 7)) * 8)];
        }

    // VT staging: thread owns keys (key0,key0+1) x dk [d0,d0+8)
    int key0 = (tid >> 3) * 2, d0 = (tid & 7) * 8;
    unsigned* vtw[8];
    #pragma unroll
    for (int j = 0; j < 8; j++) {
        int dk = d0 + j;
        int ch = (key0 >> 3) ^ (dk & 7) ^ ((dk >> 3) & 7);
        vtw[j] = (unsigned*)((char*)VT + dk*128 + ch*16 + (key0 & 7)*2);
    }

    // Kt staging src params (2 GLD16 per thread)
    int krow[2], kc8[2];
    #pragma unroll
    for (int i = 0; i < 2; i++) {
        int idx = i*256 + tid;
        krow[i] = idx >> 3;
        kc8[i]  = ((idx & 7) ^ (krow[i] & 7)) * 8;
    }

    // P buffer addresses (per wave, per group)
    char* pbw[2] = { (char*)&Pb[w][0][0], (char*)&Pb[w][1][0] };
    int pwoff[4], proff[2];
    #pragma unroll
    for (int nt = 0; nt < 4; nt++)
        pwoff[nt] = c*128 + (((2*nt + (quad >> 1)) ^ (c & 7)) * 16) + (quad & 1)*8;
    #pragma unroll
    for (int kh = 0; kh < 2; kh++)
        proff[kh] = c*128 + (((4*kh + quad) ^ (c & 7)) * 16);

    const unsigned* mrp[2] = {nullptr, nullptr};
    if (HAS_MASK) {
        mrp[0] = mbits + (size_t)(b*SEQ + q0 + 32*w + c) * (SEQ/32);
        mrp[1] = mrp[0] + (size_t)16 * (SEQ/32);
    }
    int qsh = quad * 4;

    f4_t o[2][4];
    #pragma unroll
    for (int g = 0; g < 2; g++)
        #pragma unroll
        for (int mt = 0; mt < 4; mt++) o[g][mt] = (f4_t){0.f,0.f,0.f,0.f};
    float m_[2] = {-INFINITY, -INFINITY}, l_[2] = {0.f, 0.f};

    for (int kt = 0; kt < SEQ/64; kt++) {
        int k0 = kt * 64;
        __syncthreads();
        // stage K
        const __hip_bfloat16* Kg = K + ((size_t)(b*SEQ + k0)) * D_MODEL + h*DK;
        GLD16(Kg + (size_t)krow[0]*D_MODEL + kc8[0], (char*)Kt + (size_t)(w*64) * 16);
        GLD16(Kg + (size_t)krow[1]*D_MODEL + kc8[1], (char*)Kt + (size_t)(256 + w*64) * 16);
        // stage V transposed (pair-packed b32, lane-varying XOR -> 2 words/bank, free)
        {
            const __hip_bfloat16* Vg = V + ((size_t)(b*SEQ + k0 + key0)) * D_MODEL + h*DK + d0;
            bf8_t v0 = *(const bf8_t*)Vg;
            bf8_t v1 = *(const bf8_t*)(Vg + D_MODEL);
            const unsigned* v0u = (const unsigned*)&v0;
            const unsigned* v1u = (const unsigned*)&v1;
            #pragma unroll
            for (int dw = 0; dw < 4; dw++) {
                *vtw[2*dw]     = __builtin_amdgcn_perm(v1u[dw], v0u[dw], 0x05040100u);
                *vtw[2*dw + 1] = __builtin_amdgcn_perm(v1u[dw], v0u[dw], 0x07060302u);
            }
        }
        __syncthreads();

        // --- S^T = K Q^T : 64 keys x 2x16 queries; K-frags reused across groups ---
        f4_t s[2][4];
        #pragma unroll
        for (int nt = 0; nt < 4; nt++) { s[0][nt] = (f4_t){0.f,0.f,0.f,0.f}; s[1][nt] = (f4_t){0.f,0.f,0.f,0.f}; }
        #pragma unroll
        for (int nt = 0; nt < 4; nt++)
            #pragma unroll
            for (int kh = 0; kh < 2; kh++) {
                bf8_t kf = *kp[nt][kh];
                s[0][nt] = __builtin_amdgcn_mfma_f32_16x16x32_bf16(kf, qf[0][kh], s[0][nt], 0, 0, 0);
                s[1][nt] = __builtin_amdgcn_mfma_f32_16x16x32_bf16(kf, qf[1][kh], s[1][nt], 0, 0, 0);
            }

        // --- per-group online softmax + P^T to LDS ---
        #pragma unroll
        for (int g = 0; g < 2; g++) {
            unsigned wq0 = 0xffffffffu, wq1 = 0xffffffffu;
            if (HAS_MASK) {
                uint2 mw = *(const uint2*)(mrp[g] + kt*2);
                wq0 = mw.x >> qsh; wq1 = mw.y >> qsh;
            }
            float mx = -INFINITY;
            #pragma unroll
            for (int nt = 0; nt < 4; nt++)
                #pragma unroll
                for (int r = 0; r < 4; r++) mx = fmaxf(mx, s[g][nt][r]);
            mx = fmaxf(mx, __shfl_xor(mx, 16));
            mx = fmaxf(mx, __shfl_xor(mx, 32));
            float mn = fmaxf(m_[g], mx);
            float alpha = exp2f(m_[g] - mn);
            m_[g] = mn;

            float rs = 0.f;
            #pragma unroll
            for (int nt = 0; nt < 4; nt++)
                #pragma unroll
                for (int r = 0; r < 4; r++) {
                    float p = exp2f(s[g][nt][r] - mn);
                    if (HAS_MASK) {
                        unsigned sel = (nt < 2) ? wq0 : wq1;
                        if (!((sel >> ((nt & 1)*16 + r)) & 1u)) p = 0.f;
                    }
                    s[g][nt][r] = p;
                    rs += p;
                }
            rs += __shfl_xor(rs, 16);
            rs += __shfl_xor(rs, 32);
            l_[g] = l_[g] * alpha + rs;
            #pragma unroll
            for (int mt = 0; mt < 4; mt++) o[g][mt] *= alpha;

            #pragma unroll
            for (int nt = 0; nt < 4; nt++) {
                unsigned pk0 = __builtin_amdgcn_perm(fbits(s[g][nt][1]), fbits(s[g][nt][0]), 0x07060302u);
                unsigned pk1 = __builtin_amdgcn_perm(fbits(s[g][nt][3]), fbits(s[g][nt][2]), 0x07060302u);
                *(uint2*)(pbw[g] + pwoff[nt]) = make_uint2(pk0, pk1);
            }
        }

        // --- O^T += V^T P^T ; V-frags reused across groups ---
        #pragma unroll
        for (int kh = 0; kh < 2; kh++) {
            bf8_t pfA = *(const bf8_t*)(pbw[0] + proff[kh]);
            bf8_t pfB = *(const bf8_t*)(pbw[1] + proff[kh]);
            #pragma unroll
            for (int mt = 0; mt < 4; mt++) {
                bf8_t vf = *vp[mt][kh];
                o[0][mt] = __builtin_amdgcn_mfma_f32_16x16x32_bf16(vf, pfA, o[0][mt], 0, 0, 0);
                o[1][mt] = __builtin_amdgcn_mfma_f32_16x16x32_bf16(vf, pfB, o[1][mt], 0, 0, 0);
            }
        }
    }

    // --- epilogue: Xout[q][dk] += O ; o holds O^T: row=dk=quad*4+r(+16mt), col=q=c ---
    #pragma unroll
    for (int g = 0; g < 2; g++) {
        float il = 1.f / l_[g];
        size_t rb = ((size_t)(b*SEQ + q0 + 32*w + 16*g + c)) * D_MODEL + h*DK;
        #pragma unroll
        for (int mt = 0; mt < 4; mt++)
            #pragma unroll
            for (int r = 0; r < 4; r++)
                Xout[rb + 16*mt + quad*4 + r] += o[g][mt][r] * il;
    }
}

// ---------------- MFMA GEMM1: bufH = relu(A @ W1T^T + b1), bf16 out ----------------
__global__ __launch_bounds__(256, 2)
void gemm_relu_k(const __hip_bfloat16* __restrict__ A, const __hip_bfloat16* __restrict__ BT,
                 const void* __restrict__ bias, const int* __restrict__ flagp,
                 __hip_bfloat16* __restrict__ C, int Ksz, int Nsz) {
    int f32 = *flagp;
    __shared__ __hip_bfloat16 As[128 * 64];
    __shared__ __hip_bfloat16 Bs[128 * 64];
    int tid  = threadIdx.x;
    int w    = tid >> 6;
    int c    = tid & 15;
    int quad = (tid >> 4) & 3;
    int wy = w >> 1, wx = w & 1;
    int r0 = blockIdx.y * 128, c0 = blockIdx.x * 128;

    f4_t acc[4][4];
    #pragma unroll
    for (int i = 0; i < 4; i++)
        #pragma unroll
        for (int j = 0; j < 4; j++) acc[i][j] = (f4_t){0.f,0.f,0.f,0.f};

    for (int k0 = 0; k0 < Ksz; k0 += 64) {
        __syncthreads();
        #pragma unroll
        for (int i = 0; i < 4; i++) {
            int idx = i*256 + tid;
            int row = idx >> 3, c8 = idx & 7;
            GLD16(A  + (size_t)(r0 + row) * Ksz + k0 + ((c8 ^ (row & 7)) * 8),
                  (char*)As + (size_t)(i*256 + w*64) * 16);
            GLD16(BT + (size_t)(c0 + row) * Ksz + k0 + ((c8 ^ (row & 7)) * 8),
                  (char*)Bs + (size_t)(i*256 + w*64) * 16);
        }
        __syncthreads();

        #pragma unroll
        for (int kh = 0; kh < 2; kh++) {
            bf8_t af[4], bf[4];
            #pragma unroll
            for (int mt = 0; mt < 4; mt++) {
                int row = wy*64 + mt*16 + c;
                af[mt] = *(const bf8_t*)&As[row*64 + (((kh*4 + quad) ^ (row & 7)) * 8)];
            }
            #pragma unroll
            for (int nt = 0; nt < 4; nt++) {
                int row = wx*64 + nt*16 + c;
                bf[nt] = *(const bf8_t*)&Bs[row*64 + (((kh*4 + quad) ^ (row & 7)) * 8)];
            }
            #pragma unroll
            for (int mt = 0; mt < 4; mt++)
                #pragma unroll
                for (int nt = 0; nt < 4; nt++)
                    acc[mt][nt] = __builtin_amdgcn_mfma_f32_16x16x32_bf16(af[mt], bf[nt], acc[mt][nt], 0, 0, 0);
        }
    }

    #pragma unroll
    for (int mt = 0; mt < 4; mt++)
        #pragma unroll
        for (int nt = 0; nt < 4; nt++) {
            int col = c0 + wx*64 + nt*16 + c;
            float bv = ldf(bias, col, f32);
            #pragma unroll
            for (int r = 0; r < 4; r++) {
                int m = r0 + wy*64 + mt*16 + quad*4 + r;
                C[(size_t)m * Nsz + col] = __float2bfloat16(fmaxf(acc[mt][nt][r] + bv, 0.f));
            }
        }
}

// ---------------- MFMA GEMM2: out = resid + A @ W2T^T + b2 (flagged dtype out) ----------------
__global__ __launch_bounds__(256, 2)
void gemm_out_k(const __hip_bfloat16* __restrict__ A, const __hip_bfloat16* __restrict__ BT,
                const void* __restrict__ bias, const float* __restrict__ resid,
                const int* __restrict__ flagp, void* __restrict__ out, int Ksz, int Nsz) {
    int f32 = *flagp;
    __shared__ __hip_bfloat16 As[128 * 64];
    __shared__ __hip_bfloat16 Bs[128 * 64];
    int tid  = threadIdx.x;
    int w    = tid >> 6;
    int c    = tid & 15;
    int quad = (tid >> 4) & 3;
    int wy = w >> 1, wx = w & 1;
    int r0 = blockIdx.y * 128, c0 = blockIdx.x * 128;

    f4_t acc[4][4];
    #pragma unroll
    for (int i = 0; i < 4; i++)
        #pragma unroll
        for (int j = 0; j < 4; j++) acc[i][j] = (f4_t){0.f,0.f,0.f,0.f};

    for (int k0 = 0; k0 < Ksz; k0 += 64) {
        __syncthreads();
        #pragma unroll
        for (int i = 0; i < 4; i++) {
            int idx = i*256 + tid;
            int row = idx >> 3, c8 = idx & 7;
            GLD16(A  + (size_t)(r0 + row) * Ksz + k0 + ((c8 ^ (row & 7)) * 8),
                  (char*)As + (size_t)(i*256 + w*64) * 16);
            GLD16(BT + (size_t)(c0 + row) * Ksz + k0 + ((c8 ^ (row & 7)) * 8),
                  (char*)Bs + (size_t)(i*256 + w*64) * 16);
        }
        __syncthreads();

        #pragma unroll
        for (int kh = 0; kh < 2; kh++) {
            bf8_t af[4], bf[4];
            #pragma unroll
            for (int mt = 0; mt < 4; mt++) {
                int row = wy*64 + mt*16 + c;
                af[mt] = *(const bf8_t*)&As[row*64 + (((kh*4 + quad) ^ (row & 7)) * 8)];
            }
            #pragma unroll
            for (int nt = 0; nt < 4; nt++) {
                int row = wx*64 + nt*16 + c;
                bf[nt] = *(const bf8_t*)&Bs[row*64 + (((kh*4 + quad) ^ (row & 7)) * 8)];
            }
            #pragma unroll
            for (int mt = 0; mt < 4; mt++)
                #pragma unroll
                for (int nt = 0; nt < 4; nt++)
                    acc[mt][nt] = __builtin_amdgcn_mfma_f32_16x16x32_bf16(af[mt], bf[nt], acc[mt][nt], 0, 0, 0);
        }
    }

    #pragma unroll
    for (int mt = 0; mt < 4; mt++)
        #pragma unroll
        for (int nt = 0; nt < 4; nt++) {
            int col = c0 + wx*64 + nt*16 + c;
            float bv = ldf(bias, col, f32);
            #pragma unroll
            for (int r = 0; r < 4; r++) {
                int m = r0 + wy*64 + mt*16 + quad*4 + r;
                float v = acc[mt][nt][r] + bv + resid[(size_t)m * Nsz + col];
                if (f32) ((float*)out)[(size_t)m * Nsz + col] = v;
                else     ((__hip_bfloat16*)out)[(size_t)m * Nsz + col] = __float2bfloat16(v);
            }
        }
}

// ---------------- launch ----------------
extern "C" void kernel_launch(void* const* d_in, const int* in_sizes, int n_in,
                              void* d_out, int out_size, void* d_ws, size_t ws_size,
                              hipStream_t stream) {
    const void* x    = d_in[0];
    const void* enc  = d_in[1];
    const int*  mask = (const int*)d_in[2];
    const void* ln1g = d_in[3];
    const void* ln1b = d_in[4];
    const void* ln2g = d_in[5];
    const void* ln2b = d_in[6];
    const void* ln3g = d_in[7];
    const void* ln3b = d_in[8];
    const void* W1   = d_in[9];
    const void* b1   = d_in[10];
    const void* W2   = d_in[11];
    const void* b2   = d_in[12];

    char* ws = (char*)d_ws;
    float*          bufX  = (float*)ws;                                // 16MB fp32 residual
    __hip_bfloat16* bufQ  = (__hip_bfloat16*)(ws + (16u<<20));         // 8MB LN out bf16
    __hip_bfloat16* bufE  = (__hip_bfloat16*)(ws + (24u<<20));         // 8MB encoder bf16
    __hip_bfloat16* bufH  = (__hip_bfloat16*)(ws + (32u<<20));         // 16MB FFN hidden bf16
    __hip_bfloat16* W1T   = (__hip_bfloat16*)(ws + (48u<<20));         // 1MB
    __hip_bfloat16* W2T   = (__hip_bfloat16*)(ws + (49u<<20));         // 1MB
    unsigned*       mbits = (unsigned*)(ws + (50u<<20));               // 2MB
    int*            flags = (int*)(ws + (52u<<20));

    dim3 blk(256);
    detect_k<<<1, blk, 0, stream>>>((const uint4*)x, flags);
    maskbits_k<<<NTOK/4, blk, 0, stream>>>(mask, mbits);
    cast_bf16_k<<<NELEM/256, blk, 0, stream>>>(enc, flags, bufE, NELEM);
    transpose_k<<<dim3(D_FF/32, D_MODEL/32), blk, 0, stream>>>(W1, flags, W1T, D_MODEL, D_FF);
    transpose_k<<<dim3(D_MODEL/32, D_FF/32), blk, 0, stream>>>(W2, flags, W2T, D_FF, D_MODEL);

    // LN1 (fused input cast) + masked self-attention + residual
    ln_first_k<<<NTOK/4, blk, 0, stream>>>(x, ln1g, ln1b, flags, bufX, bufQ);
    attn_mfma_k<true><<<BATCH*HEADS*(SEQ/128), blk, 0, stream>>>(bufQ, bufQ, bufQ, mbits, bufX);
    // LN2 + cross-attention + residual
    layernorm_k<<<NTOK/4, blk, 0, stream>>>(bufX, ln2g, ln2b, flags, bufQ);
    attn_mfma_k<false><<<BATCH*HEADS*(SEQ/128), blk, 0, stream>>>(bufQ, bufE, bufE, nullptr, bufX);
    // LN3 + FFN + residual (+final cast fused into GEMM2)
    layernorm_k<<<NTOK/4, blk, 0, stream>>>(bufX, ln3g, ln3b, flags, bufQ);
    gemm_relu_k<<<dim3(D_FF/128, NTOK/128), blk, 0, stream>>>(bufQ, W1T, b1, flags, bufH, D_MODEL, D_FF);
    gemm_out_k<<<dim3(D_MODEL/128, NTOK/128), blk, 0, stream>>>(bufH, W2T, b2, bufX, flags, d_out, D_FF, D_MODEL);
}

// Round 6
// 373.455 us; speedup vs baseline: 9.3326x; 1.1635x over previous
//
#include <hip/hip_runtime.h>
#include <hip/hip_bf16.h>

#define D_MODEL 512
#define HEADS   8
#define DK      64
#define D_FF    1024
#define SEQ     2048
#define BATCH   4
#define NTOK    (BATCH*SEQ)          // 8192 rows
#define NELEM   (NTOK*D_MODEL)       // 4,194,304

#define QSCALE  0.18033688011112042f // 0.125 * log2(e)
#define MFIX    40.0f                // fixed softmax shift (exact: exp2(s-C)/sum)

typedef __attribute__((ext_vector_type(8))) short bf8_t;   // 8 bf16 (4 VGPRs)
typedef __attribute__((ext_vector_type(4))) float f4_t;    // 4 fp32

#define GLD16(gp, lp) __builtin_amdgcn_global_load_lds( \
    (const __attribute__((address_space(1))) void*)(gp), \
    (__attribute__((address_space(3))) void*)(lp), 16, 0, 0)

__device__ __forceinline__ float ldf(const void* p, size_t i, int f32) {
    return f32 ? ((const float*)p)[i] : __bfloat162float(((const __hip_bfloat16*)p)[i]);
}
__device__ __forceinline__ short f2bf(float f) {
    union { __hip_bfloat16 h; short s; } u; u.h = __float2bfloat16(f); return u.s;
}
__device__ __forceinline__ float bf2f(short s) {
    return __uint_as_float(((unsigned)(unsigned short)s) << 16);
}
__device__ __forceinline__ unsigned fbits(float f) { return __float_as_uint(f); }

// ---------------- dtype detector (bf16 vs fp32 inputs) ----------------
__global__ void detect_k(const uint4* __restrict__ w, int* __restrict__ flags) {
    __shared__ int found;
    if (threadIdx.x == 0) found = 0;
    __syncthreads();
    int hit = 0;
    for (int i = threadIdx.x; i < 4096; i += 256) {
        uint4 u = w[i];
        if (((u.x & 0x7F80u) == 0x7F80u) || ((u.y & 0x7F80u) == 0x7F80u) ||
            ((u.z & 0x7F80u) == 0x7F80u) || ((u.w & 0x7F80u) == 0x7F80u)) hit = 1;
    }
    if (hit) atomicOr(&found, 1);
    __syncthreads();
    if (threadIdx.x == 0) flags[0] = found ? 1 : 0;
}

// ---------------- fused prep: enc cast | maskbits | W1T | W2T ----------------
__device__ __forceinline__ void transpose_body(const void* src, __hip_bfloat16* dst,
                                               int K, int N, int bxi, int byi, int f32,
                                               __hip_bfloat16 (*t)[33]) {
    int bx = bxi * 32, by = byi * 32;
    int tx = threadIdx.x & 31, ty = threadIdx.x >> 5;
    #pragma unroll
    for (int j = 0; j < 32; j += 8)
        t[ty + j][tx] = __float2bfloat16(ldf(src, (size_t)(by + ty + j) * N + bx + tx, f32));
    __syncthreads();
    #pragma unroll
    for (int j = 0; j < 32; j += 8)
        dst[(size_t)(bx + ty + j) * K + by + tx] = t[tx][ty + j];
}

__global__ __launch_bounds__(256)
void prep_k(const void* __restrict__ enc, const int* __restrict__ mask,
            const void* __restrict__ W1, const void* __restrict__ W2,
            const int* __restrict__ flagp,
            __hip_bfloat16* __restrict__ bufE, unsigned* __restrict__ mb,
            __hip_bfloat16* __restrict__ W1T, __hip_bfloat16* __restrict__ W2T) {
    __shared__ __hip_bfloat16 t[32][33];
    int f32 = *flagp;
    int bid = blockIdx.x;
    if (bid < 16384) {                       // enc -> bf16
        int i = bid * 256 + threadIdx.x;
        bufE[i] = __float2bfloat16(ldf(enc, i, f32));
    } else if (bid < 18432) {                // mask -> bits
        int row  = (bid - 16384) * 4 + (threadIdx.x >> 6);
        int lane = threadIdx.x & 63;
        const int* mr = mask + (size_t)row * SEQ;
        for (int it = 0; it < SEQ/64; it++) {
            unsigned long long bal = __ballot(mr[it*64 + lane] != 0);
            if (lane == 0)  mb[(size_t)row*(SEQ/32) + it*2]     = (unsigned)bal;
            if (lane == 32) mb[(size_t)row*(SEQ/32) + it*2 + 1] = (unsigned)(bal >> 32);
        }
    } else if (bid < 18944) {                // W1T[N=1024][K=512]
        int lb = bid - 18432;
        transpose_body(W1, W1T, D_MODEL, D_FF, lb & 31, lb >> 5, f32, t);
    } else {                                 // W2T[N=512][K=1024]
        int lb = bid - 18944;
        transpose_body(W2, W2T, D_FF, D_MODEL, lb & 15, lb >> 4, f32, t);
    }
}

// ---------------- LN1 fused with input cast ----------------
__global__ __launch_bounds__(256)
void ln_first_k(const void* __restrict__ x, const void* __restrict__ g,
                const void* __restrict__ b, const int* __restrict__ flagp,
                float* __restrict__ xout, __hip_bfloat16* __restrict__ y) {
    int f32  = *flagp;
    int row  = blockIdx.x * 4 + (threadIdx.x >> 6);
    int lane = threadIdx.x & 63;
    size_t base = (size_t)row * D_MODEL;
    float v[8];
    float s = 0.f;
    #pragma unroll
    for (int i = 0; i < 8; i++) { v[i] = ldf(x, base + lane + i*64, f32); s += v[i]; }
    #pragma unroll
    for (int off = 32; off; off >>= 1) s += __shfl_xor(s, off);
    float mu = s * (1.f / D_MODEL);
    float ss = 0.f;
    #pragma unroll
    for (int i = 0; i < 8; i++) { float d = v[i] - mu; ss += d * d; }
    #pragma unroll
    for (int off = 32; off; off >>= 1) ss += __shfl_xor(ss, off);
    float rstd = rsqrtf(ss * (1.f / D_MODEL) + 1e-5f);
    #pragma unroll
    for (int i = 0; i < 8; i++) {
        int c = lane + i*64;
        xout[base + c] = v[i];
        y[base + c] = __float2bfloat16((v[i] - mu) * rstd * ldf(g, c, f32) + ldf(b, c, f32));
    }
}

// ---------------- layernorm (fp32 in, bf16 out) ----------------
__global__ __launch_bounds__(256)
void layernorm_k(const float* __restrict__ x, const void* __restrict__ g,
                 const void* __restrict__ b, const int* __restrict__ flagp,
                 __hip_bfloat16* __restrict__ y) {
    int f32  = *flagp;
    int row  = blockIdx.x * 4 + (threadIdx.x >> 6);
    int lane = threadIdx.x & 63;
    const float* xr = x + (size_t)row * D_MODEL;
    float v[8];
    float s = 0.f;
    #pragma unroll
    for (int i = 0; i < 8; i++) { v[i] = xr[lane + i*64]; s += v[i]; }
    #pragma unroll
    for (int off = 32; off; off >>= 1) s += __shfl_xor(s, off);
    float mu = s * (1.f / D_MODEL);
    float ss = 0.f;
    #pragma unroll
    for (int i = 0; i < 8; i++) { float d = v[i] - mu; ss += d * d; }
    #pragma unroll
    for (int off = 32; off; off >>= 1) ss += __shfl_xor(ss, off);
    float rstd = rsqrtf(ss * (1.f / D_MODEL) + 1e-5f);
    __hip_bfloat16* yr = y + (size_t)row * D_MODEL;
    #pragma unroll
    for (int i = 0; i < 8; i++) {
        int c = lane + i*64;
        yr[c] = __float2bfloat16((v[i] - mu) * rstd * ldf(g, c, f32) + ldf(b, c, f32));
    }
}

__device__ __forceinline__ bf8_t prescale_q(bf8_t q) {
    bf8_t r;
    #pragma unroll
    for (int j = 0; j < 8; j++) r[j] = f2bf(bf2f(q[j]) * QSCALE);
    return r;
}

// ---------------- MFMA flash attention: fixed-max softmax, 2-tile phases ----------------
// Block: 128 q of one (b,h); 4 waves x 32 q (2 groups of 16).
// S^T = K·Q^T; p = exp2(s - MFIX) (exact softmax shift); l via ones-row MFMA.
template<bool HAS_MASK>
__global__ __launch_bounds__(256, 2)
void attn_mfma_k(const __hip_bfloat16* __restrict__ Q, const __hip_bfloat16* __restrict__ K,
                 const __hip_bfloat16* __restrict__ V, const unsigned* __restrict__ mbits,
                 float* __restrict__ Xout) {
    int bid = blockIdx.x;
    int qt = bid & 15;
    int h  = (bid >> 4) & 7;
    int b  = bid >> 7;
    int q0 = qt * 128;
    int tid  = threadIdx.x;
    int w    = tid >> 6;
    int lane = tid & 63;
    int c    = lane & 15;
    int quad = lane >> 4;

    __shared__ __hip_bfloat16 Kt[2][64 * 64];     // [key][dk], chunk XOR by key&7
    __shared__ __hip_bfloat16 VT[2][64 * 64];     // [dk][key], chunk XOR by (dk&7)^((dk>>3)&7)
    __shared__ __hip_bfloat16 Pb[4][2][16 * 64];  // per-wave per-group P^T, XOR by q&7

    // Q fragments (B-operand), prescaled
    bf8_t qf[2][2];
    #pragma unroll
    for (int g = 0; g < 2; g++) {
        const __hip_bfloat16* qrp = Q + ((size_t)(b*SEQ + q0 + 32*w + 16*g + c)) * D_MODEL + h*DK;
        qf[g][0] = prescale_q(*(const bf8_t*)(qrp + quad*8));
        qf[g][1] = prescale_q(*(const bf8_t*)(qrp + 32 + quad*8));
    }

    // kt-invariant LDS byte offsets (into buffer 0; +8192*t for buffer t)
    int kpo[4][2], vpo[4][2];
    #pragma unroll
    for (int t = 0; t < 4; t++)
        #pragma unroll
        for (int kh = 0; kh < 2; kh++) {
            int row = 16*t + c;
            kpo[t][kh] = (row*64 + (((4*kh + quad) ^ (row & 7)) * 8)) * 2;
            vpo[t][kh] = (row*64 + (((4*kh + quad) ^ (row & 7) ^ ((row >> 3) & 7)) * 8)) * 2;
        }

    // VT staging: thread owns keys (key0,key0+1) x dk [d0,d0+8)
    int key0 = (tid >> 3) * 2, d0 = (tid & 7) * 8;
    int vtwo[8];
    #pragma unroll
    for (int j = 0; j < 8; j++) {
        int dk = d0 + j;
        int ch = (key0 >> 3) ^ (dk & 7) ^ ((dk >> 3) & 7);
        vtwo[j] = dk*128 + ch*16 + (key0 & 7)*2;
    }

    // Kt staging src params
    int krow[2], kc8[2];
    #pragma unroll
    for (int i = 0; i < 2; i++) {
        int idx = i*256 + tid;
        krow[i] = idx >> 3;
        kc8[i]  = ((idx & 7) ^ (krow[i] & 7)) * 8;
    }

    // P buffer byte offsets (per wave, per group)
    char* pbw[2] = { (char*)&Pb[w][0][0], (char*)&Pb[w][1][0] };
    int pwoff[4], proff[2];
    #pragma unroll
    for (int nt = 0; nt < 4; nt++)
        pwoff[nt] = c*128 + (((2*nt + (quad >> 1)) ^ (c & 7)) * 16) + (quad & 1)*8;
    #pragma unroll
    for (int kh = 0; kh < 2; kh++)
        proff[kh] = c*128 + (((4*kh + quad) ^ (c & 7)) * 16);

    const unsigned* mrp[2] = {nullptr, nullptr};
    if (HAS_MASK) {
        mrp[0] = mbits + (size_t)(b*SEQ + q0 + 32*w + c) * (SEQ/32);
        mrp[1] = mrp[0] + (size_t)16 * (SEQ/32);
    }
    int qsh = quad * 4;

    // ones A-frag (row 0 only) for l row-sum MFMA
    short onev = (c == 0) ? (short)0x3F80 : (short)0;
    bf8_t ones = {onev, onev, onev, onev, onev, onev, onev, onev};

    f4_t o[2][4];
    #pragma unroll
    for (int g = 0; g < 2; g++)
        #pragma unroll
        for (int mt = 0; mt < 4; mt++) o[g][mt] = (f4_t){0.f,0.f,0.f,0.f};
    f4_t l_acc[2] = {(f4_t){0.f,0.f,0.f,0.f}, (f4_t){0.f,0.f,0.f,0.f}};

    const size_t kvbase = (size_t)b * SEQ * D_MODEL + (size_t)h * DK;

    for (int ph = 0; ph < SEQ/128; ph++) {
        int k0 = ph * 128;
        __syncthreads();   // both buffers free
        // ---- stage 2 K tiles + 2 V^T tiles ----
        #pragma unroll
        for (int t = 0; t < 2; t++) {
            const __hip_bfloat16* Kg = K + kvbase + (size_t)(k0 + t*64) * D_MODEL;
            GLD16(Kg + (size_t)krow[0]*D_MODEL + kc8[0], (char*)&Kt[t][0] + (w*64) * 16);
            GLD16(Kg + (size_t)krow[1]*D_MODEL + kc8[1], (char*)&Kt[t][0] + (256 + w*64) * 16);
        }
        #pragma unroll
        for (int t = 0; t < 2; t++) {
            const __hip_bfloat16* Vg = V + kvbase + (size_t)(k0 + t*64 + key0) * D_MODEL + d0;
            bf8_t v0 = *(const bf8_t*)Vg;
            bf8_t v1 = *(const bf8_t*)(Vg + D_MODEL);
            const unsigned* v0u = (const unsigned*)&v0;
            const unsigned* v1u = (const unsigned*)&v1;
            char* vb = (char*)&VT[t][0];
            #pragma unroll
            for (int dw = 0; dw < 4; dw++) {
                *(unsigned*)(vb + vtwo[2*dw])     = __builtin_amdgcn_perm(v1u[dw], v0u[dw], 0x05040100u);
                *(unsigned*)(vb + vtwo[2*dw + 1]) = __builtin_amdgcn_perm(v1u[dw], v0u[dw], 0x07060302u);
            }
        }
        __syncthreads();   // staging visible

        // ---- compute both tiles, no barriers ----
        #pragma unroll
        for (int t = 0; t < 2; t++) {
            const char* ktb = (const char*)&Kt[t][0];
            const char* vtb = (const char*)&VT[t][0];

            // S^T = K Q^T
            f4_t s[2][4];
            #pragma unroll
            for (int nt = 0; nt < 4; nt++) { s[0][nt] = (f4_t){0.f,0.f,0.f,0.f}; s[1][nt] = (f4_t){0.f,0.f,0.f,0.f}; }
            #pragma unroll
            for (int nt = 0; nt < 4; nt++)
                #pragma unroll
                for (int kh = 0; kh < 2; kh++) {
                    bf8_t kf = *(const bf8_t*)(ktb + kpo[nt][kh]);
                    s[0][nt] = __builtin_amdgcn_mfma_f32_16x16x32_bf16(kf, qf[0][kh], s[0][nt], 0, 0, 0);
                    s[1][nt] = __builtin_amdgcn_mfma_f32_16x16x32_bf16(kf, qf[1][kh], s[1][nt], 0, 0, 0);
                }

            // fixed-max exp + mask + pack -> per-wave LDS
            #pragma unroll
            for (int g = 0; g < 2; g++) {
                unsigned wq0 = 0xffffffffu, wq1 = 0xffffffffu;
                if (HAS_MASK) {
                    uint2 mw = *(const uint2*)(mrp[g] + ((k0 + t*64) >> 5));
                    wq0 = mw.x >> qsh; wq1 = mw.y >> qsh;
                }
                #pragma unroll
                for (int nt = 0; nt < 4; nt++) {
                    #pragma unroll
                    for (int r = 0; r < 4; r++) {
                        float p = exp2f(s[g][nt][r] - MFIX);
                        if (HAS_MASK) {
                            unsigned sel = (nt < 2) ? wq0 : wq1;
                            if (!((sel >> ((nt & 1)*16 + r)) & 1u)) p = 0.f;
                        }
                        s[g][nt][r] = p;
                    }
                    unsigned pk0 = __builtin_amdgcn_perm(fbits(s[g][nt][1]), fbits(s[g][nt][0]), 0x07060302u);
                    unsigned pk1 = __builtin_amdgcn_perm(fbits(s[g][nt][3]), fbits(s[g][nt][2]), 0x07060302u);
                    *(uint2*)(pbw[g] + pwoff[nt]) = make_uint2(pk0, pk1);
                }
            }

            // O^T += V^T P^T ; l += ones·P^T
            #pragma unroll
            for (int kh = 0; kh < 2; kh++) {
                bf8_t pfA = *(const bf8_t*)(pbw[0] + proff[kh]);
                bf8_t pfB = *(const bf8_t*)(pbw[1] + proff[kh]);
                l_acc[0] = __builtin_amdgcn_mfma_f32_16x16x32_bf16(ones, pfA, l_acc[0], 0, 0, 0);
                l_acc[1] = __builtin_amdgcn_mfma_f32_16x16x32_bf16(ones, pfB, l_acc[1], 0, 0, 0);
                #pragma unroll
                for (int mt = 0; mt < 4; mt++) {
                    bf8_t vf = *(const bf8_t*)(vtb + vpo[mt][kh]);
                    o[0][mt] = __builtin_amdgcn_mfma_f32_16x16x32_bf16(vf, pfA, o[0][mt], 0, 0, 0);
                    o[1][mt] = __builtin_amdgcn_mfma_f32_16x16x32_bf16(vf, pfB, o[1][mt], 0, 0, 0);
                }
            }
        }
    }

    // epilogue: l broadcast from (quad=0, lane=c) reg0; Xout += O/l
    #pragma unroll
    for (int g = 0; g < 2; g++) {
        float lq = __shfl(l_acc[g][0], c);
        float il = 1.f / fmaxf(lq, 1e-35f);
        size_t rb = ((size_t)(b*SEQ + q0 + 32*w + 16*g + c)) * D_MODEL + h*DK;
        #pragma unroll
        for (int mt = 0; mt < 4; mt++)
            #pragma unroll
            for (int r = 0; r < 4; r++)
                Xout[rb + 16*mt + quad*4 + r] += o[g][mt][r] * il;
    }
}

// ---------------- MFMA GEMM1: bufH = relu(A @ W1T^T + b1), bf16 out; 128x128 ----------------
__global__ __launch_bounds__(256, 2)
void gemm_relu_k(const __hip_bfloat16* __restrict__ A, const __hip_bfloat16* __restrict__ BT,
                 const void* __restrict__ bias, const int* __restrict__ flagp,
                 __hip_bfloat16* __restrict__ C, int Ksz, int Nsz) {
    int f32 = *flagp;
    __shared__ __hip_bfloat16 As[128 * 64];
    __shared__ __hip_bfloat16 Bs[128 * 64];
    int tid  = threadIdx.x;
    int w    = tid >> 6;
    int c    = tid & 15;
    int quad = (tid >> 4) & 3;
    int wy = w >> 1, wx = w & 1;
    int r0 = blockIdx.y * 128, c0 = blockIdx.x * 128;

    f4_t acc[4][4];
    #pragma unroll
    for (int i = 0; i < 4; i++)
        #pragma unroll
        for (int j = 0; j < 4; j++) acc[i][j] = (f4_t){0.f,0.f,0.f,0.f};

    for (int k0 = 0; k0 < Ksz; k0 += 64) {
        __syncthreads();
        #pragma unroll
        for (int i = 0; i < 4; i++) {
            int idx = i*256 + tid;
            int row = idx >> 3, c8 = idx & 7;
            GLD16(A  + (size_t)(r0 + row) * Ksz + k0 + ((c8 ^ (row & 7)) * 8),
                  (char*)As + (size_t)(i*256 + w*64) * 16);
            GLD16(BT + (size_t)(c0 + row) * Ksz + k0 + ((c8 ^ (row & 7)) * 8),
                  (char*)Bs + (size_t)(i*256 + w*64) * 16);
        }
        __syncthreads();

        #pragma unroll
        for (int kh = 0; kh < 2; kh++) {
            bf8_t af[4], bf[4];
            #pragma unroll
            for (int mt = 0; mt < 4; mt++) {
                int row = wy*64 + mt*16 + c;
                af[mt] = *(const bf8_t*)&As[row*64 + (((kh*4 + quad) ^ (row & 7)) * 8)];
            }
            #pragma unroll
            for (int nt = 0; nt < 4; nt++) {
                int row = wx*64 + nt*16 + c;
                bf[nt] = *(const bf8_t*)&Bs[row*64 + (((kh*4 + quad) ^ (row & 7)) * 8)];
            }
            #pragma unroll
            for (int mt = 0; mt < 4; mt++)
                #pragma unroll
                for (int nt = 0; nt < 4; nt++)
                    acc[mt][nt] = __builtin_amdgcn_mfma_f32_16x16x32_bf16(af[mt], bf[nt], acc[mt][nt], 0, 0, 0);
        }
    }

    #pragma unroll
    for (int mt = 0; mt < 4; mt++)
        #pragma unroll
        for (int nt = 0; nt < 4; nt++) {
            int col = c0 + wx*64 + nt*16 + c;
            float bv = ldf(bias, col, f32);
            #pragma unroll
            for (int r = 0; r < 4; r++) {
                int m = r0 + wy*64 + mt*16 + quad*4 + r;
                C[(size_t)m * Nsz + col] = __float2bfloat16(fmaxf(acc[mt][nt][r] + bv, 0.f));
            }
        }
}

// ---------------- MFMA GEMM2: out = resid + A @ W2T^T + b2; 128x64 tiles ----------------
__global__ __launch_bounds__(256, 2)
void gemm_out_k(const __hip_bfloat16* __restrict__ A, const __hip_bfloat16* __restrict__ BT,
                const void* __restrict__ bias, const float* __restrict__ resid,
                const int* __restrict__ flagp, void* __restrict__ out, int Ksz, int Nsz) {
    int f32 = *flagp;
    __shared__ __hip_bfloat16 As[128 * 64];
    __shared__ __hip_bfloat16 Bs[64 * 64];
    int tid  = threadIdx.x;
    int w    = tid >> 6;
    int c    = tid & 15;
    int quad = (tid >> 4) & 3;
    int r0 = blockIdx.y * 128, c0 = blockIdx.x * 64;

    f4_t acc[2][4];
    #pragma unroll
    for (int i = 0; i < 2; i++)
        #pragma unroll
        for (int j = 0; j < 4; j++) acc[i][j] = (f4_t){0.f,0.f,0.f,0.f};

    for (int k0 = 0; k0 < Ksz; k0 += 64) {
        __syncthreads();
        #pragma unroll
        for (int i = 0; i < 4; i++) {
            int idx = i*256 + tid;
            int row = idx >> 3, c8 = idx & 7;
            GLD16(A + (size_t)(r0 + row) * Ksz + k0 + ((c8 ^ (row & 7)) * 8),
                  (char*)As + (size_t)(i*256 + w*64) * 16);
        }
        #pragma unroll
        for (int i = 0; i < 2; i++) {
            int idx = i*256 + tid;
            int row = idx >> 3, c8 = idx & 7;
            GLD16(BT + (size_t)(c0 + row) * Ksz + k0 + ((c8 ^ (row & 7)) * 8),
                  (char*)Bs + (size_t)(i*256 + w*64) * 16);
        }
        __syncthreads();

        #pragma unroll
        for (int kh = 0; kh < 2; kh++) {
            bf8_t af[2], bf[4];
            #pragma unroll
            for (int mt = 0; mt < 2; mt++) {
                int row = w*32 + mt*16 + c;
                af[mt] = *(const bf8_t*)&As[row*64 + (((kh*4 + quad) ^ (row & 7)) * 8)];
            }
            #pragma unroll
            for (int nt = 0; nt < 4; nt++) {
                int row = nt*16 + c;
                bf[nt] = *(const bf8_t*)&Bs[row*64 + (((kh*4 + quad) ^ (row & 7)) * 8)];
            }
            #pragma unroll
            for (int mt = 0; mt < 2; mt++)
                #pragma unroll
                for (int nt = 0; nt < 4; nt++)
                    acc[mt][nt] = __builtin_amdgcn_mfma_f32_16x16x32_bf16(af[mt], bf[nt], acc[mt][nt], 0, 0, 0);
        }
    }

    #pragma unroll
    for (int mt = 0; mt < 2; mt++)
        #pragma unroll
        for (int nt = 0; nt < 4; nt++) {
            int col = c0 + nt*16 + c;
            float bv = ldf(bias, col, f32);
            #pragma unroll
            for (int r = 0; r < 4; r++) {
                int m = r0 + w*32 + mt*16 + quad*4 + r;
                float v = acc[mt][nt][r] + bv + resid[(size_t)m * Nsz + col];
                if (f32) ((float*)out)[(size_t)m * Nsz + col] = v;
                else     ((__hip_bfloat16*)out)[(size_t)m * Nsz + col] = __float2bfloat16(v);
            }
        }
}

// ---------------- launch ----------------
extern "C" void kernel_launch(void* const* d_in, const int* in_sizes, int n_in,
                              void* d_out, int out_size, void* d_ws, size_t ws_size,
                              hipStream_t stream) {
    const void* x    = d_in[0];
    const void* enc  = d_in[1];
    const int*  mask = (const int*)d_in[2];
    const void* ln1g = d_in[3];
    const void* ln1b = d_in[4];
    const void* ln2g = d_in[5];
    const void* ln2b = d_in[6];
    const void* ln3g = d_in[7];
    const void* ln3b = d_in[8];
    const void* W1   = d_in[9];
    const void* b1   = d_in[10];
    const void* W2   = d_in[11];
    const void* b2   = d_in[12];

    char* ws = (char*)d_ws;
    float*          bufX  = (float*)ws;                                // 16MB fp32 residual
    __hip_bfloat16* bufQ  = (__hip_bfloat16*)(ws + (16u<<20));         // 8MB LN out bf16
    __hip_bfloat16* bufE  = (__hip_bfloat16*)(ws + (24u<<20));         // 8MB encoder bf16
    __hip_bfloat16* bufH  = (__hip_bfloat16*)(ws + (32u<<20));         // 16MB FFN hidden bf16
    __hip_bfloat16* W1T   = (__hip_bfloat16*)(ws + (48u<<20));         // 1MB
    __hip_bfloat16* W2T   = (__hip_bfloat16*)(ws + (49u<<20));         // 1MB
    unsigned*       mbits = (unsigned*)(ws + (50u<<20));               // 2MB
    int*            flags = (int*)(ws + (52u<<20));

    dim3 blk(256);
    detect_k<<<1, blk, 0, stream>>>((const uint4*)x, flags);
    prep_k<<<19456, blk, 0, stream>>>(enc, mask, W1, W2, flags, bufE, mbits, W1T, W2T);

    // LN1 (fused input cast) + masked self-attention + residual
    ln_first_k<<<NTOK/4, blk, 0, stream>>>(x, ln1g, ln1b, flags, bufX, bufQ);
    attn_mfma_k<true><<<BATCH*HEADS*(SEQ/128), blk, 0, stream>>>(bufQ, bufQ, bufQ, mbits, bufX);
    // LN2 + cross-attention + residual
    layernorm_k<<<NTOK/4, blk, 0, stream>>>(bufX, ln2g, ln2b, flags, bufQ);
    attn_mfma_k<false><<<BATCH*HEADS*(SEQ/128), blk, 0, stream>>>(bufQ, bufE, bufE, nullptr, bufX);
    // LN3 + FFN + residual (+final cast fused into GEMM2)
    layernorm_k<<<NTOK/4, blk, 0, stream>>>(bufX, ln3g, ln3b, flags, bufQ);
    gemm_relu_k<<<dim3(D_FF/128, NTOK/128), blk, 0, stream>>>(bufQ, W1T, b1, flags, bufH, D_MODEL, D_FF);
    gemm_out_k<<<dim3(D_MODEL/64, NTOK/128), blk, 0, stream>>>(bufH, W2T, b2, bufX, flags, d_out, D_FF, D_MODEL);
}